// Round 5
// baseline (562.008 us; speedup 1.0000x reference)
//
#include <hip/hip_runtime.h>
#include <hip/hip_bf16.h>

// PCGraphConv: iterative predictive-coding message passing.
// N_V=2000, N_E=500000, BATCH=32, T=5, lr=0.1, sensory = first 784 vertices.
// R4: DENSIFY. Graph is 12.5% dense -> sum multi-edges into dense WA[dst][src]
// (fp32, 16MB) and WB[src-784][dst] (9.7MB, non-sensory rows only) with
// uncontended fp32 atomics (no sort/cursors). Each step = two small dense
// VALU GEMMs (K=2000) with fx/err tables bf16 in padded [batch][k] rows
// (uint4 = 8 elems per load), weights exact fp32, tanh fused into the
// back-GEMM epilogue. Falls back to the proven R3 CSR path if ws too small.

#define N_V     2000
#define N_SENS  784
#define N_INT   (N_V - N_SENS)   // 1216
#define N_E     500000
#define T_STEPS 5
#define LR_VAL  0.1f
#define NVB     (N_V * 32)       // 64000
#define NVH     (N_V * 16)       // 32000
#define FXS     2016             // padded u16 row stride for fx_g/err_g (16B-aligned)

__device__ __forceinline__ float bits_to_f32(unsigned u) {
    union { unsigned u; float f; } c; c.u = u; return c.f;
}
__device__ __forceinline__ unsigned f32_to_bits(float f) {
    union { float f; unsigned u; } c; c.f = f; return c.u;
}
__device__ __forceinline__ unsigned short f32_to_bf16(float f) {
    unsigned u = f32_to_bits(f);
    return (unsigned short)((u + 0x7FFFu + ((u >> 16) & 1u)) >> 16);  // RNE
}
__device__ __forceinline__ float bf16_to_f32(unsigned short s) {
    return bits_to_f32((unsigned)s << 16);
}

// ------------------------- dense path ------------------------------------

__global__ void k_zero_f32(float* a, int n) {
    for (int t = blockIdx.x * blockDim.x + threadIdx.x; t < n; t += gridDim.x * blockDim.x)
        a[t] = 0.f;
}

__global__ void k_accum(const int* __restrict__ src, const int* __restrict__ dst,
                        const float* __restrict__ w,
                        float* __restrict__ WA, float* __restrict__ WB) {
    int e = blockIdx.x * blockDim.x + threadIdx.x;
    if (e < N_E) {
        int s = src[e], d = dst[e];
        float wf = w[e];
        atomicAdd(&WA[d * N_V + s], wf);
        if (s >= N_SENS) atomicAdd(&WB[(s - N_SENS) * N_V + d], wf);
    }
}

// input [batch][vertex] fp32 -> internal [vertex][32] fp32
__global__ void k_cast_in(const float* __restrict__ vin, float* __restrict__ v) {
    int t = blockIdx.x * blockDim.x + threadIdx.x;
    if (t < NVB) {
        int i = t >> 5, b = t & 31;
        v[t] = vin[b * N_V + i];
    }
}

// fx_g[b][i] = bf16(tanh(v[i][b])), row stride FXS
__global__ void k_fx_init(const float* __restrict__ v, unsigned short* __restrict__ fx_g) {
    int t = blockIdx.x * blockDim.x + threadIdx.x;
    if (t < NVB) {
        int i = t >> 5, b = t & 31;
        fx_g[b * FXS + i] = f32_to_bf16(tanhf(v[t]));
    }
}

// err[i][b] = v[i][b] - sum_k WA[i][k] * fx[k][b]
// grid 500 = 2 batch-halves x 250 vertex-tiles(8); block 256 = 8v x (16b x 2kh).
// kh lanes split K in halves, combined with shfl_xor(16).
__global__ __launch_bounds__(256) void k_gemm_err(
        const float* __restrict__ WA, const unsigned short* __restrict__ fx_g,
        const float* __restrict__ v_cur, unsigned short* __restrict__ err_g) {
    int bh = blockIdx.x / 250;
    int vt = blockIdx.x % 250;
    int vv = vt * 8 + (threadIdx.x >> 5);
    int lane = threadIdx.x & 31;
    int b = bh * 16 + (lane & 15);
    int kh = lane >> 4;
    const uint4*  fxp = (const uint4*)(fx_g + b * FXS + kh * 1000);
    const float4* wp  = (const float4*)(WA + vv * N_V + kh * 1000);
    float sum = 0.f;
    #pragma unroll 5
    for (int i = 0; i < 125; ++i) {
        uint4 f = fxp[i];
        float4 wa = wp[2 * i], wb = wp[2 * i + 1];
        sum += bits_to_f32(f.x << 16)        * wa.x;
        sum += bits_to_f32(f.x & 0xFFFF0000u) * wa.y;
        sum += bits_to_f32(f.y << 16)        * wa.z;
        sum += bits_to_f32(f.y & 0xFFFF0000u) * wa.w;
        sum += bits_to_f32(f.z << 16)        * wb.x;
        sum += bits_to_f32(f.z & 0xFFFF0000u) * wb.y;
        sum += bits_to_f32(f.w << 16)        * wb.z;
        sum += bits_to_f32(f.w & 0xFFFF0000u) * wb.w;
    }
    sum += __shfl_xor(sum, 16, 64);
    if (kh == 0) {
        int idx = (vv << 5) + b;
        float e = v_cur[idx] - sum;
        err_g[b * FXS + vv] = f32_to_bf16(e);
    }
}

// back[j][b] = sum_k WB[j-784][k] * err[k][b];
// v[j][b] -= lr*(err_j - (1-fx_j^2)*back); fx_j = tanh(v_new) fused.
// grid 304 = 2 batch-halves x 152 vertex-tiles(8) over j in [784,2000).
__global__ __launch_bounds__(256) void k_gemm_back(
        const float* __restrict__ WB, const unsigned short* __restrict__ err_g,
        unsigned short* __restrict__ fx_g, float* __restrict__ v_cur) {
    int bh = blockIdx.x / 152;
    int vt = blockIdx.x % 152;
    int r  = vt * 8 + (threadIdx.x >> 5);       // WB row
    int j  = N_SENS + r;                        // vertex id
    int lane = threadIdx.x & 31;
    int b = bh * 16 + (lane & 15);
    int kh = lane >> 4;
    const uint4*  erp = (const uint4*)(err_g + b * FXS + kh * 1000);
    const float4* wp  = (const float4*)(WB + r * N_V + kh * 1000);
    float sum = 0.f;
    #pragma unroll 5
    for (int i = 0; i < 125; ++i) {
        uint4 f = erp[i];
        float4 wa = wp[2 * i], wb = wp[2 * i + 1];
        sum += bits_to_f32(f.x << 16)        * wa.x;
        sum += bits_to_f32(f.x & 0xFFFF0000u) * wa.y;
        sum += bits_to_f32(f.y << 16)        * wa.z;
        sum += bits_to_f32(f.y & 0xFFFF0000u) * wa.w;
        sum += bits_to_f32(f.z << 16)        * wb.x;
        sum += bits_to_f32(f.z & 0xFFFF0000u) * wb.y;
        sum += bits_to_f32(f.w << 16)        * wb.z;
        sum += bits_to_f32(f.w & 0xFFFF0000u) * wb.w;
    }
    sum += __shfl_xor(sum, 16, 64);
    if (kh == 0) {
        int idx = (j << 5) + b;
        float e0  = bf16_to_f32(err_g[b * FXS + j]);
        float fxv = bf16_to_f32(fx_g[b * FXS + j]);
        float vn = v_cur[idx] - LR_VAL * (e0 - (1.f - fxv * fxv) * sum);
        v_cur[idx] = vn;
        fx_g[b * FXS + j] = f32_to_bf16(tanhf(vn));
    }
}

// internal [vertex][32] -> output [batch][vertex] fp32
__global__ void k_out(const float* __restrict__ v, float* __restrict__ out) {
    int t = blockIdx.x * blockDim.x + threadIdx.x;
    if (t < NVB) {
        int b = t / N_V;
        int i = t - b * N_V;
        out[t] = v[(i << 5) + b];
    }
}

// ------------------------- fallback path (R3 CSR, proven) ----------------

__global__ void k_zero_i32(int* a, int n) {
    int t = blockIdx.x * blockDim.x + threadIdx.x;
    if (t < n) a[t] = 0;
}

__global__ void k_hist(const int* __restrict__ src, const int* __restrict__ dst,
                       int* cnt_dst, int* cnt_src) {
    int e = blockIdx.x * blockDim.x + threadIdx.x;
    if (e < N_E) {
        atomicAdd(&cnt_dst[dst[e]], 1);
        atomicAdd(&cnt_src[src[e]], 1);
    }
}

__global__ __launch_bounds__(1024) void k_scan(int* cnt_a, int* rp_a,
                                               int* cnt_b, int* rp_b) {
    __shared__ int sh[1024];
    int t = threadIdx.x;
    for (int pass = 0; pass < 2; ++pass) {
        int* cnt = pass ? cnt_b : cnt_a;
        int* rp  = pass ? rp_b  : rp_a;
        int i0 = 2 * t, i1 = 2 * t + 1;
        int c0 = (i0 < N_V) ? cnt[i0] : 0;
        int c1 = (i1 < N_V) ? cnt[i1] : 0;
        __syncthreads();
        sh[t] = c0 + c1;
        __syncthreads();
        for (int off = 1; off < 1024; off <<= 1) {
            int v = (t >= off) ? sh[t - off] : 0;
            __syncthreads();
            sh[t] += v;
            __syncthreads();
        }
        int incl = sh[t];
        int e0 = incl - (c0 + c1);
        int e1 = e0 + c0;
        if (i0 <= N_V) rp[i0] = e0;
        if (i1 <= N_V) rp[i1] = e1;
        if (i0 < N_V) cnt[i0] = e0;
        if (i1 < N_V) cnt[i1] = e1;
    }
}

__global__ void k_scatter(const int* __restrict__ src, const int* __restrict__ dst,
                          const float* __restrict__ w,
                          int* cur_dst, int* cur_src,
                          unsigned* __restrict__ pk_dst, unsigned* __restrict__ pk_src) {
    int e = blockIdx.x * blockDim.x + threadIdx.x;
    if (e < N_E) {
        int s = src[e], d = dst[e];
        unsigned wbits = (unsigned)f32_to_bf16(w[e]);
        int p = atomicAdd(&cur_dst[d], 1);
        pk_dst[p] = (wbits << 16) | (unsigned)s;
        int q = atomicAdd(&cur_src[s], 1);
        pk_src[q] = (wbits << 16) | (unsigned)d;
    }
}

__global__ void k_fx_csr(const float* __restrict__ v, unsigned short* __restrict__ fx) {
    int t = blockIdx.x * blockDim.x + threadIdx.x;
    if (t < NVB) {
        int i = t >> 5, b = t & 31;
        int h = b >> 4, b16 = b & 15;
        fx[h * NVH + i * 16 + b16] = f32_to_bf16(tanhf(v[t]));
    }
}

__global__ __launch_bounds__(256) void k_pred_err(
        const float* __restrict__ v, const unsigned short* __restrict__ fx,
        const int* __restrict__ rp, const unsigned* __restrict__ pk,
        unsigned short* __restrict__ err) {
    __shared__ unsigned short tab[NVH];
    int h  = blockIdx.x / 250;
    int vg = blockIdx.x % 250;
    {
        const uint4* g = (const uint4*)(fx + h * NVH);
        uint4* l = (uint4*)tab;
        for (int i = threadIdx.x; i < NVH / 8; i += 256) l[i] = g[i];
    }
    __syncthreads();
    int wave = threadIdx.x >> 6;
    int lane = threadIdx.x & 63;
    int b16 = lane & 15, epar = lane >> 4;
    for (int k = 0; k < 2; ++k) {
        int vid = vg * 8 + wave * 2 + k;
        int beg = rp[vid], end = rp[vid + 1];
        float sum = 0.f;
        for (int e = beg + epar; e < end; e += 4) {
            unsigned p = pk[e];
            float w = bits_to_f32(p & 0xFFFF0000u);
            int nb = (int)(p & 0xFFFFu);
            sum += w * bf16_to_f32(tab[nb * 16 + b16]);
        }
        sum += __shfl_xor(sum, 16, 64);
        sum += __shfl_xor(sum, 32, 64);
        if (epar == 0) {
            float vo = v[(vid << 5) + h * 16 + b16];
            err[h * NVH + vid * 16 + b16] = f32_to_bf16(vo - sum);
        }
    }
}

__global__ __launch_bounds__(256) void k_back_upd(
        const unsigned short* __restrict__ fx, const unsigned short* __restrict__ err,
        const int* __restrict__ rp, const unsigned* __restrict__ pk,
        float* __restrict__ v) {
    __shared__ unsigned short tab[NVH];
    int h  = blockIdx.x / 152;
    int vg = blockIdx.x % 152;
    {
        const uint4* g = (const uint4*)(err + h * NVH);
        uint4* l = (uint4*)tab;
        for (int i = threadIdx.x; i < NVH / 8; i += 256) l[i] = g[i];
    }
    __syncthreads();
    int wave = threadIdx.x >> 6;
    int lane = threadIdx.x & 63;
    int b16 = lane & 15, epar = lane >> 4;
    for (int k = 0; k < 2; ++k) {
        int vid = N_SENS + vg * 8 + wave * 2 + k;
        if (vid >= N_V) continue;
        int beg = rp[vid], end = rp[vid + 1];
        float sum = 0.f;
        for (int e = beg + epar; e < end; e += 4) {
            unsigned p = pk[e];
            float w = bits_to_f32(p & 0xFFFF0000u);
            int nb = (int)(p & 0xFFFFu);
            sum += w * bf16_to_f32(tab[nb * 16 + b16]);
        }
        sum += __shfl_xor(sum, 16, 64);
        sum += __shfl_xor(sum, 32, 64);
        if (epar == 0) {
            float e0  = bf16_to_f32(tab[vid * 16 + b16]);
            float fxv = bf16_to_f32(fx[h * NVH + vid * 16 + b16]);
            float dv = e0 - (1.f - fxv * fxv) * sum;
            v[(vid << 5) + h * 16 + b16] -= LR_VAL * dv;
        }
    }
}

// ------------------------- host -----------------------------------------

extern "C" void kernel_launch(void* const* d_in, const int* in_sizes, int n_in,
                              void* d_out, int out_size, void* d_ws, size_t ws_size,
                              hipStream_t stream) {
    const float* vals = (const float*)d_in[0];
    const float* wts  = (const float*)d_in[1];
    const int* ei = (const int*)d_in[2];
    const int* src = ei;
    const int* dst = ei + N_E;
    float* out = (float*)d_out;

    const int EB = (N_E + 255) / 256;

    // dense-path ws requirement
    const size_t WA_N = (size_t)N_V * N_V;          // 4,000,000 f32
    const size_t WB_N = (size_t)N_INT * N_V;        // 2,432,000 f32
    const size_t need = (WA_N + WB_N + NVB) * 4 + 2 * (size_t)32 * FXS * 2 + 4096;

    if (ws_size >= need) {
        float* WA    = (float*)d_ws;                         // 16 MB
        float* WB    = WA + WA_N;                            // 9.7 MB
        float* v_cur = WB + WB_N;                            // 256 KB
        unsigned short* fx_g  = (unsigned short*)(v_cur + NVB);  // 32*FXS
        unsigned short* err_g = fx_g + 32 * FXS;

        k_zero_f32<<<1024, 256, 0, stream>>>(WA, (int)(WA_N + WB_N)); // WA+WB contiguous
        k_accum<<<EB, 256, 0, stream>>>(src, dst, wts, WA, WB);
        k_cast_in<<<250, 256, 0, stream>>>(vals, v_cur);
        k_fx_init<<<250, 256, 0, stream>>>(v_cur, fx_g);

        for (int t = 0; t < T_STEPS; ++t) {
            k_gemm_err<<<500, 256, 0, stream>>>(WA, fx_g, v_cur, err_g);
            k_gemm_back<<<304, 256, 0, stream>>>(WB, err_g, fx_g, v_cur);
        }
        k_out<<<250, 256, 0, stream>>>(v_cur, out);
    } else {
        // R3 CSR fallback (~4.6 MB)
        float* v_cur = (float*)d_ws;
        unsigned short* fx_g  = (unsigned short*)(v_cur + NVB);
        unsigned short* err_g = fx_g + NVB;
        int* rp_dst  = (int*)(err_g + NVB);
        int* rp_src  = rp_dst + 2048;
        int* cur_dst = rp_src + 2048;
        int* cur_src = cur_dst + 2048;
        unsigned* pk_dst = (unsigned*)(cur_src + 2048);
        unsigned* pk_src = pk_dst + N_E;

        k_zero_i32<<<16, 256, 0, stream>>>(cur_dst, 4096);
        k_hist<<<EB, 256, 0, stream>>>(src, dst, cur_dst, cur_src);
        k_scan<<<1, 1024, 0, stream>>>(cur_dst, rp_dst, cur_src, rp_src);
        k_scatter<<<EB, 256, 0, stream>>>(src, dst, wts, cur_dst, cur_src,
                                          pk_dst, pk_src);
        k_cast_in<<<250, 256, 0, stream>>>(vals, v_cur);
        for (int t = 0; t < T_STEPS; ++t) {
            k_fx_csr<<<250, 256, 0, stream>>>(v_cur, fx_g);
            k_pred_err<<<500, 256, 0, stream>>>(v_cur, fx_g, rp_dst, pk_dst, err_g);
            k_back_upd<<<304, 256, 0, stream>>>(fx_g, err_g, rp_src, pk_src, v_cur);
        }
        k_out<<<250, 256, 0, stream>>>(v_cur, out);
    }
}

// Round 6
// 213.855 us; speedup vs baseline: 2.6280x; 2.6280x over previous
//
#include <hip/hip_runtime.h>
#include <hip/hip_bf16.h>

// PCGraphConv: iterative predictive-coding message passing.
// N_V=2000, N_SENS=784, N_E=500000, BATCH=32, T=5, lr=0.1.
// R5: dense weights + MFMA GEMMs.
//  - WA fp32 master [2048][2016] built by 500K uncontended atomicAdds.
//  - WB bf16 [1280][2016] = transpose of WA's non-sensory columns (LDS tiles),
//    replacing 304K extra atomics.
//  - Each step: GEMM1 err = v - WA·fx  and GEMM2 back = WB·err with
//    v_mfma_f32_16x16x32_bf16; block = 4 waves K-splitting one 16-row tile,
//    LDS reduce, fused epilogues (err store / v update + tanh + frag repack).
//  - fx/err kept in MFMA B-fragment layout (packed by producers).
// Fallback: proven R4 CSR path if ws too small.

#define N_V     2000
#define N_SENS  784
#define N_INT   (N_V - N_SENS)   // 1216
#define N_E     500000
#define T_STEPS 5
#define LR_VAL  0.1f
#define NVB     (N_V * 32)       // 64000
#define NVH     (N_V * 16)       // 32000
#define MP      2048             // padded M (WA rows)
#define KP      2016             // padded K (63 chunks of 32)
#define MP2     1280             // padded M for WB (1216 -> 80 tiles)
#define NCH     63               // K chunks
#define FRAG_N  (NCH * 2 * 64 * 8)   // 64512 u16 per frag table

typedef float  f32x4 __attribute__((ext_vector_type(4)));
typedef short  s16x8 __attribute__((ext_vector_type(8)));

__device__ __forceinline__ float bits_to_f32(unsigned u) {
    union { unsigned u; float f; } c; c.u = u; return c.f;
}
__device__ __forceinline__ unsigned f32_to_bits(float f) {
    union { float f; unsigned u; } c; c.f = f; return c.u;
}
__device__ __forceinline__ unsigned short f32_to_bf16(float f) {
    unsigned u = f32_to_bits(f);
    return (unsigned short)((u + 0x7FFFu + ((u >> 16) & 1u)) >> 16);  // RNE
}
__device__ __forceinline__ float bf16_to_f32(unsigned short s) {
    return bits_to_f32((unsigned)s << 16);
}

// B-fragment position (u16 index) for element (k, n) of a [KP x 32] operand.
__device__ __forceinline__ int fragpos(int k, int n) {
    int c = k >> 5, q = (k >> 3) & 3, j = k & 7, nh = n >> 4;
    return (((c * 2 + nh) * 64) + q * 16 + (n & 15)) * 8 + j;
}

// ------------------------- dense/MFMA path -------------------------------

__global__ void k_zero_u4(uint4* p, int n4) {
    uint4 z = {0u, 0u, 0u, 0u};
    for (int t = blockIdx.x * blockDim.x + threadIdx.x; t < n4; t += gridDim.x * blockDim.x)
        p[t] = z;
}

__global__ void k_accum(const int* __restrict__ src, const int* __restrict__ dst,
                        const float* __restrict__ w, float* __restrict__ WA) {
    int e = blockIdx.x * blockDim.x + threadIdx.x;
    if (e < N_E) {
        atomicAdd(&WA[(size_t)dst[e] * KP + src[e]], w[e]);
    }
}

// WB[r][c] = bf16(WA[c][784+r]), r<1216(+pad), c<2016. 32x32 LDS tiles.
__global__ __launch_bounds__(256) void k_tr(const float* __restrict__ WA,
                                            unsigned short* __restrict__ WB) {
    __shared__ float t[32][33];
    int c0 = blockIdx.x * 32;          // 63 tiles over columns-of-WB (= WA rows)
    int r0 = blockIdx.y * 32;          // 38 tiles over rows-of-WB
    int tr = threadIdx.x & 31, tc = threadIdx.x >> 5;   // 32 x 8
    #pragma unroll
    for (int p = 0; p < 4; ++p) {
        int ci = tc + p * 8;
        t[ci][tr] = WA[(size_t)(c0 + ci) * KP + N_SENS + r0 + tr];
    }
    __syncthreads();
    #pragma unroll
    for (int p = 0; p < 4; ++p) {
        int ri = tc + p * 8;
        WB[(size_t)(r0 + ri) * KP + c0 + tr] = f32_to_bf16(t[tr][ri]);
    }
}

// input [batch][vertex] fp32 -> internal [vertex][32] fp32
__global__ void k_cast_in(const float* __restrict__ vin, float* __restrict__ v) {
    int t = blockIdx.x * blockDim.x + threadIdx.x;
    if (t < NVB) {
        int i = t >> 5, b = t & 31;
        v[t] = vin[b * N_V + i];
    }
}

// fx_frag[pos(i,b)] = bf16(tanh(v[i][b]))
__global__ void k_fx_init(const float* __restrict__ v, unsigned short* __restrict__ fx_frag) {
    int t = blockIdx.x * blockDim.x + threadIdx.x;
    if (t < NVB) {
        int i = t >> 5, b = t & 31;
        fx_frag[fragpos(i, b)] = f32_to_bf16(tanhf(v[t]));
    }
}

// GEMM1: err = v - WA(fp32->bf16) . fx ; 128 tiles of 16 rows, 4-wave K-split.
__global__ __launch_bounds__(256) void k_gemm1(
        const float* __restrict__ WA, const unsigned short* __restrict__ fx_frag,
        const float* __restrict__ v_cur, float* __restrict__ err_plain,
        unsigned short* __restrict__ err_frag) {
    __shared__ float red[2048];
    int tile = blockIdx.x;
    int w = threadIdx.x >> 6, l = threadIdx.x & 63;
    int row = tile * 16 + (l & 15);
    int q = l >> 4;
    int cbeg = w * 16, cend = (cbeg + 16 < NCH) ? cbeg + 16 : NCH;
    f32x4 acc0 = {0.f, 0.f, 0.f, 0.f}, acc1 = {0.f, 0.f, 0.f, 0.f};
    const float* arow = WA + (size_t)row * KP + q * 8;
    const uint4* bbase = (const uint4*)fx_frag;
    for (int c = cbeg; c < cend; ++c) {
        const float4* ap = (const float4*)(arow + c * 32);
        float4 a0 = ap[0], a1 = ap[1];
        s16x8 af;
        af[0] = (short)f32_to_bf16(a0.x); af[1] = (short)f32_to_bf16(a0.y);
        af[2] = (short)f32_to_bf16(a0.z); af[3] = (short)f32_to_bf16(a0.w);
        af[4] = (short)f32_to_bf16(a1.x); af[5] = (short)f32_to_bf16(a1.y);
        af[6] = (short)f32_to_bf16(a1.z); af[7] = (short)f32_to_bf16(a1.w);
        uint4 b0 = bbase[(c * 2) * 64 + l];
        uint4 b1 = bbase[(c * 2 + 1) * 64 + l];
        acc0 = __builtin_amdgcn_mfma_f32_16x16x32_bf16(af, *(s16x8*)&b0, acc0, 0, 0, 0);
        acc1 = __builtin_amdgcn_mfma_f32_16x16x32_bf16(af, *(s16x8*)&b1, acc1, 0, 0, 0);
    }
    float* my = &red[(w * 64 + l) * 8];
    #pragma unroll
    for (int r = 0; r < 4; ++r) { my[r] = acc0[r]; my[4 + r] = acc1[r]; }
    __syncthreads();
    if (w == 0) {
        #pragma unroll
        for (int r = 0; r < 8; ++r) {
            float s = red[l * 8 + r] + red[512 + l * 8 + r]
                    + red[1024 + l * 8 + r] + red[1536 + l * 8 + r];
            int i = tile * 16 + (l >> 4) * 4 + (r & 3);
            int b = (l & 15) + ((r >= 4) ? 16 : 0);
            int idx = (i << 5) + b;
            float e = v_cur[idx] - s;
            err_plain[idx] = e;
            if (i < N_V) err_frag[fragpos(i, b)] = f32_to_bf16(e);
        }
    }
}

// GEMM2: back = WB(bf16) . err ; 80 tiles; fused v update + tanh + fx repack.
__global__ __launch_bounds__(256) void k_gemm2(
        const unsigned short* __restrict__ WB, const unsigned short* __restrict__ err_frag,
        const float* __restrict__ err_plain, unsigned short* __restrict__ fx_frag,
        float* __restrict__ v_cur) {
    __shared__ float red[2048];
    int tile = blockIdx.x;
    int w = threadIdx.x >> 6, l = threadIdx.x & 63;
    int row = tile * 16 + (l & 15);
    int q = l >> 4;
    int cbeg = w * 16, cend = (cbeg + 16 < NCH) ? cbeg + 16 : NCH;
    f32x4 acc0 = {0.f, 0.f, 0.f, 0.f}, acc1 = {0.f, 0.f, 0.f, 0.f};
    const unsigned short* arow = WB + (size_t)row * KP + q * 8;
    const uint4* bbase = (const uint4*)err_frag;
    for (int c = cbeg; c < cend; ++c) {
        uint4 a = *(const uint4*)(arow + c * 32);
        uint4 b0 = bbase[(c * 2) * 64 + l];
        uint4 b1 = bbase[(c * 2 + 1) * 64 + l];
        acc0 = __builtin_amdgcn_mfma_f32_16x16x32_bf16(*(s16x8*)&a, *(s16x8*)&b0, acc0, 0, 0, 0);
        acc1 = __builtin_amdgcn_mfma_f32_16x16x32_bf16(*(s16x8*)&a, *(s16x8*)&b1, acc1, 0, 0, 0);
    }
    float* my = &red[(w * 64 + l) * 8];
    #pragma unroll
    for (int r = 0; r < 4; ++r) { my[r] = acc0[r]; my[4 + r] = acc1[r]; }
    __syncthreads();
    if (w == 0) {
        #pragma unroll
        for (int r = 0; r < 8; ++r) {
            float back = red[l * 8 + r] + red[512 + l * 8 + r]
                       + red[1024 + l * 8 + r] + red[1536 + l * 8 + r];
            int rr = tile * 16 + (l >> 4) * 4 + (r & 3);
            if (rr < N_INT) {
                int j = N_SENS + rr;
                int b = (l & 15) + ((r >= 4) ? 16 : 0);
                int idx = (j << 5) + b;
                float vold = v_cur[idx];
                float fxv = tanhf(vold);
                float e0 = err_plain[idx];
                float vn = vold - LR_VAL * (e0 - (1.f - fxv * fxv) * back);
                v_cur[idx] = vn;
                fx_frag[fragpos(j, b)] = f32_to_bf16(tanhf(vn));
            }
        }
    }
}

// internal [vertex][32] -> output [batch][vertex] fp32
__global__ void k_out(const float* __restrict__ v, float* __restrict__ out) {
    int t = blockIdx.x * blockDim.x + threadIdx.x;
    if (t < NVB) {
        int b = t / N_V;
        int i = t - b * N_V;
        out[t] = v[(i << 5) + b];
    }
}

// ------------------------- fallback path (R4 CSR, proven) ----------------

__global__ void k_zero_i32(int* a, int n) {
    int t = blockIdx.x * blockDim.x + threadIdx.x;
    if (t < n) a[t] = 0;
}

__global__ void k_hist(const int* __restrict__ src, const int* __restrict__ dst,
                       int* cnt_dst, int* cnt_src) {
    int e = blockIdx.x * blockDim.x + threadIdx.x;
    if (e < N_E) {
        atomicAdd(&cnt_dst[dst[e]], 1);
        atomicAdd(&cnt_src[src[e]], 1);
    }
}

__global__ __launch_bounds__(1024) void k_scan(int* cnt_a, int* rp_a,
                                               int* cnt_b, int* rp_b) {
    __shared__ int sh[1024];
    int t = threadIdx.x;
    for (int pass = 0; pass < 2; ++pass) {
        int* cnt = pass ? cnt_b : cnt_a;
        int* rp  = pass ? rp_b  : rp_a;
        int i0 = 2 * t, i1 = 2 * t + 1;
        int c0 = (i0 < N_V) ? cnt[i0] : 0;
        int c1 = (i1 < N_V) ? cnt[i1] : 0;
        __syncthreads();
        sh[t] = c0 + c1;
        __syncthreads();
        for (int off = 1; off < 1024; off <<= 1) {
            int v = (t >= off) ? sh[t - off] : 0;
            __syncthreads();
            sh[t] += v;
            __syncthreads();
        }
        int incl = sh[t];
        int e0 = incl - (c0 + c1);
        int e1 = e0 + c0;
        if (i0 <= N_V) rp[i0] = e0;
        if (i1 <= N_V) rp[i1] = e1;
        if (i0 < N_V) cnt[i0] = e0;
        if (i1 < N_V) cnt[i1] = e1;
    }
}

__global__ void k_scatter(const int* __restrict__ src, const int* __restrict__ dst,
                          const float* __restrict__ w,
                          int* cur_dst, int* cur_src,
                          unsigned* __restrict__ pk_dst, unsigned* __restrict__ pk_src) {
    int e = blockIdx.x * blockDim.x + threadIdx.x;
    if (e < N_E) {
        int s = src[e], d = dst[e];
        unsigned wbits = (unsigned)f32_to_bf16(w[e]);
        int p = atomicAdd(&cur_dst[d], 1);
        pk_dst[p] = (wbits << 16) | (unsigned)s;
        int q = atomicAdd(&cur_src[s], 1);
        pk_src[q] = (wbits << 16) | (unsigned)d;
    }
}

__global__ void k_fx_csr(const float* __restrict__ v, unsigned short* __restrict__ fx) {
    int t = blockIdx.x * blockDim.x + threadIdx.x;
    if (t < NVB) {
        int i = t >> 5, b = t & 31;
        int h = b >> 4, b16 = b & 15;
        fx[h * NVH + i * 16 + b16] = f32_to_bf16(tanhf(v[t]));
    }
}

__global__ __launch_bounds__(256) void k_pred_err(
        const float* __restrict__ v, const unsigned short* __restrict__ fx,
        const int* __restrict__ rp, const unsigned* __restrict__ pk,
        unsigned short* __restrict__ err) {
    __shared__ unsigned short tab[NVH];
    int h  = blockIdx.x / 250;
    int vg = blockIdx.x % 250;
    {
        const uint4* g = (const uint4*)(fx + h * NVH);
        uint4* l = (uint4*)tab;
        for (int i = threadIdx.x; i < NVH / 8; i += 256) l[i] = g[i];
    }
    __syncthreads();
    int wave = threadIdx.x >> 6;
    int lane = threadIdx.x & 63;
    int b16 = lane & 15, epar = lane >> 4;
    for (int k = 0; k < 2; ++k) {
        int vid = vg * 8 + wave * 2 + k;
        int beg = rp[vid], end = rp[vid + 1];
        float sum = 0.f;
        for (int e = beg + epar; e < end; e += 4) {
            unsigned p = pk[e];
            float w = bits_to_f32(p & 0xFFFF0000u);
            int nb = (int)(p & 0xFFFFu);
            sum += w * bf16_to_f32(tab[nb * 16 + b16]);
        }
        sum += __shfl_xor(sum, 16, 64);
        sum += __shfl_xor(sum, 32, 64);
        if (epar == 0) {
            float vo = v[(vid << 5) + h * 16 + b16];
            err[h * NVH + vid * 16 + b16] = f32_to_bf16(vo - sum);
        }
    }
}

__global__ __launch_bounds__(256) void k_back_upd(
        const unsigned short* __restrict__ fx, const unsigned short* __restrict__ err,
        const int* __restrict__ rp, const unsigned* __restrict__ pk,
        float* __restrict__ v) {
    __shared__ unsigned short tab[NVH];
    int h  = blockIdx.x / 152;
    int vg = blockIdx.x % 152;
    {
        const uint4* g = (const uint4*)(err + h * NVH);
        uint4* l = (uint4*)tab;
        for (int i = threadIdx.x; i < NVH / 8; i += 256) l[i] = g[i];
    }
    __syncthreads();
    int wave = threadIdx.x >> 6;
    int lane = threadIdx.x & 63;
    int b16 = lane & 15, epar = lane >> 4;
    for (int k = 0; k < 2; ++k) {
        int vid = N_SENS + vg * 8 + wave * 2 + k;
        if (vid >= N_V) continue;
        int beg = rp[vid], end = rp[vid + 1];
        float sum = 0.f;
        for (int e = beg + epar; e < end; e += 4) {
            unsigned p = pk[e];
            float w = bits_to_f32(p & 0xFFFF0000u);
            int nb = (int)(p & 0xFFFFu);
            sum += w * bf16_to_f32(tab[nb * 16 + b16]);
        }
        sum += __shfl_xor(sum, 16, 64);
        sum += __shfl_xor(sum, 32, 64);
        if (epar == 0) {
            float e0  = bf16_to_f32(tab[vid * 16 + b16]);
            float fxv = bf16_to_f32(fx[h * NVH + vid * 16 + b16]);
            float dv = e0 - (1.f - fxv * fxv) * sum;
            v[(vid << 5) + h * 16 + b16] -= LR_VAL * dv;
        }
    }
}

// ------------------------- host -----------------------------------------

extern "C" void kernel_launch(void* const* d_in, const int* in_sizes, int n_in,
                              void* d_out, int out_size, void* d_ws, size_t ws_size,
                              hipStream_t stream) {
    const float* vals = (const float*)d_in[0];
    const float* wts  = (const float*)d_in[1];
    const int* ei = (const int*)d_in[2];
    const int* src = ei;
    const int* dst = ei + N_E;
    float* out = (float*)d_out;

    const int EB = (N_E + 255) / 256;

    // dense ws layout
    const size_t WA_N = (size_t)MP * KP;            // 4,128,768 f32
    const size_t WB_N = (size_t)MP2 * KP;           // 2,580,480 u16
    const size_t need = WA_N * 4 + WB_N * 2 + 65536 * 4 * 2 + FRAG_N * 2 * 2 + 256;

    if (ws_size >= need) {
        float* WA = (float*)d_ws;                              // 16.5 MB
        unsigned short* WB = (unsigned short*)(WA + WA_N);     // 5.16 MB
        float* v_cur = (float*)(WB + WB_N);                    // 65536 f32
        float* err_plain = v_cur + 65536;                      // 65536 f32
        unsigned short* fx_frag  = (unsigned short*)(err_plain + 65536);  // 64512
        unsigned short* err_frag = fx_frag + FRAG_N;                      // 64512

        k_zero_u4<<<1024, 256, 0, stream>>>((uint4*)WA, (int)(WA_N / 4));
        k_zero_u4<<<63, 256, 0, stream>>>((uint4*)fx_frag, (FRAG_N * 2 * 2) / 16);
        k_accum<<<EB, 256, 0, stream>>>(src, dst, wts, WA);
        k_tr<<<dim3(63, 38), 256, 0, stream>>>(WA, WB);
        k_cast_in<<<250, 256, 0, stream>>>(vals, v_cur);
        k_fx_init<<<250, 256, 0, stream>>>(v_cur, fx_frag);

        for (int t = 0; t < T_STEPS; ++t) {
            k_gemm1<<<MP / 16, 256, 0, stream>>>(WA, fx_frag, v_cur, err_plain, err_frag);
            k_gemm2<<<MP2 / 16, 256, 0, stream>>>(WB, err_frag, err_plain, fx_frag, v_cur);
        }
        k_out<<<250, 256, 0, stream>>>(v_cur, out);
    } else {
        // R4 CSR fallback (~4.6 MB)
        float* v_cur = (float*)d_ws;
        unsigned short* fx_g  = (unsigned short*)(v_cur + NVB);
        unsigned short* err_g = fx_g + NVB;
        int* rp_dst  = (int*)(err_g + NVB);
        int* rp_src  = rp_dst + 2048;
        int* cur_dst = rp_src + 2048;
        int* cur_src = cur_dst + 2048;
        unsigned* pk_dst = (unsigned*)(cur_src + 2048);
        unsigned* pk_src = pk_dst + N_E;

        k_zero_i32<<<16, 256, 0, stream>>>(cur_dst, 4096);
        k_hist<<<EB, 256, 0, stream>>>(src, dst, cur_dst, cur_src);
        k_scan<<<1, 1024, 0, stream>>>(cur_dst, rp_dst, cur_src, rp_src);
        k_scatter<<<EB, 256, 0, stream>>>(src, dst, wts, cur_dst, cur_src,
                                          pk_dst, pk_src);
        k_cast_in<<<250, 256, 0, stream>>>(vals, v_cur);
        for (int t = 0; t < T_STEPS; ++t) {
            k_fx_csr<<<250, 256, 0, stream>>>(v_cur, fx_g);
            k_pred_err<<<500, 256, 0, stream>>>(v_cur, fx_g, rp_dst, pk_dst, err_g);
            k_back_upd<<<304, 256, 0, stream>>>(fx_g, err_g, rp_src, pk_src, v_cur);
        }
        k_out<<<250, 256, 0, stream>>>(v_cur, out);
    }
}

// Round 7
// 193.963 us; speedup vs baseline: 2.8975x; 1.1026x over previous
//
#include <hip/hip_runtime.h>
#include <hip/hip_bf16.h>

// PCGraphConv: iterative predictive-coding message passing.
// N_V=2000, N_SENS=784, N_E=500000, BATCH=32, T=5, lr=0.1.
// R6: dense MFMA path, tightened.
//  - WA fp32 master [2048][2016] via 500K uncontended atomicAdds.
//  - WAbf = bf16(WA) once -> GEMM1 A-stream halves; no in-loop cvt.
//  - WB bf16 [1216][2016] = transpose of WA non-sensory columns (LDS tiles).
//  - GEMM1 grid (128,2), GEMM2 grid (76,2): batch halves split across blocks
//    -> all 256 CUs busy. 4 waves/block K-split, LDS reduce (stride-5 pad).
//  - fx/err live in MFMA B-fragment layout; epilogues fuse err store /
//    v-update + tanh + frag repack. Zero pass covers WA + frag tables only.
// Fallback: proven R4 CSR path if ws too small.

#define N_V     2000
#define N_SENS  784
#define N_INT   (N_V - N_SENS)   // 1216
#define N_E     500000
#define T_STEPS 5
#define LR_VAL  0.1f
#define NVB     (N_V * 32)       // 64000
#define NVH     (N_V * 16)       // 32000
#define MP      2048             // padded M (WA rows)
#define KP      2016             // padded K (63 chunks of 32)
#define MP2     1216             // WB rows (76 tiles of 16, exact)
#define NCH     63               // K chunks
#define FRAG_N  (NCH * 2 * 64 * 8)   // 64512 u16 per frag table

typedef float  f32x4 __attribute__((ext_vector_type(4)));
typedef short  s16x8 __attribute__((ext_vector_type(8)));

__device__ __forceinline__ float bits_to_f32(unsigned u) {
    union { unsigned u; float f; } c; c.u = u; return c.f;
}
__device__ __forceinline__ unsigned f32_to_bits(float f) {
    union { float f; unsigned u; } c; c.f = f; return c.u;
}
__device__ __forceinline__ unsigned short f32_to_bf16(float f) {
    unsigned u = f32_to_bits(f);
    return (unsigned short)((u + 0x7FFFu + ((u >> 16) & 1u)) >> 16);  // RNE
}
__device__ __forceinline__ float bf16_to_f32(unsigned short s) {
    return bits_to_f32((unsigned)s << 16);
}

// B-fragment u16 index for element (k, n) of a [KP x 32] operand.
__device__ __forceinline__ int fragpos(int k, int n) {
    int c = k >> 5, q = (k >> 3) & 3, j = k & 7, nh = n >> 4;
    return (((c * 2 + nh) * 64) + q * 16 + (n & 15)) * 8 + j;
}

// ------------------------- dense/MFMA path -------------------------------

__global__ void k_zero_u4(uint4* p, int n4) {
    uint4 z = {0u, 0u, 0u, 0u};
    for (int t = blockIdx.x * blockDim.x + threadIdx.x; t < n4; t += gridDim.x * blockDim.x)
        p[t] = z;
}

__global__ void k_accum(const int* __restrict__ src, const int* __restrict__ dst,
                        const float* __restrict__ w, float* __restrict__ WA) {
    int e = blockIdx.x * blockDim.x + threadIdx.x;
    if (e < N_E) {
        atomicAdd(&WA[(size_t)dst[e] * KP + src[e]], w[e]);
    }
}

// WAbf = bf16(WA), 8 elems/thread-iter
__global__ void k_cvt(const float* __restrict__ WA, unsigned short* __restrict__ WAbf,
                      int n8) {
    for (int t = blockIdx.x * blockDim.x + threadIdx.x; t < n8; t += gridDim.x * blockDim.x) {
        const float4* s = (const float4*)WA + 2 * t;
        float4 a0 = s[0], a1 = s[1];
        unsigned short r[8];
        r[0] = f32_to_bf16(a0.x); r[1] = f32_to_bf16(a0.y);
        r[2] = f32_to_bf16(a0.z); r[3] = f32_to_bf16(a0.w);
        r[4] = f32_to_bf16(a1.x); r[5] = f32_to_bf16(a1.y);
        r[6] = f32_to_bf16(a1.z); r[7] = f32_to_bf16(a1.w);
        ((uint4*)WAbf)[t] = *(const uint4*)r;
    }
}

// WB[r][c] = bf16(WA[c][784+r]), r<1216, c<2016. 32x32 LDS tiles.
__global__ __launch_bounds__(256) void k_tr(const float* __restrict__ WA,
                                            unsigned short* __restrict__ WB) {
    __shared__ float t[32][33];
    int c0 = blockIdx.x * 32;
    int r0 = blockIdx.y * 32;
    int tr = threadIdx.x & 31, tc = threadIdx.x >> 5;   // 32 x 8
    #pragma unroll
    for (int p = 0; p < 4; ++p) {
        int ci = tc + p * 8;
        t[ci][tr] = WA[(size_t)(c0 + ci) * KP + N_SENS + r0 + tr];
    }
    __syncthreads();
    #pragma unroll
    for (int p = 0; p < 4; ++p) {
        int ri = tc + p * 8;
        WB[(size_t)(r0 + ri) * KP + c0 + tr] = f32_to_bf16(t[tr][ri]);
    }
}

// input [batch][vertex] fp32 -> v_cur [vertex][32] fp32 + fx_frag (bf16 tanh)
__global__ void k_init(const float* __restrict__ vin, float* __restrict__ v,
                       unsigned short* __restrict__ fx_frag) {
    int t = blockIdx.x * blockDim.x + threadIdx.x;
    if (t < NVB) {
        int i = t >> 5, b = t & 31;
        float x = vin[b * N_V + i];
        v[t] = x;
        fx_frag[fragpos(i, b)] = f32_to_bf16(tanhf(x));
    }
}

// GEMM1: err = v - WAbf . fx ; grid (128 tiles, 2 batch-halves).
__global__ __launch_bounds__(256) void k_gemm1(
        const unsigned short* __restrict__ WAbf, const unsigned short* __restrict__ fx_frag,
        const float* __restrict__ v_cur, float* __restrict__ err_plain,
        unsigned short* __restrict__ err_frag) {
    __shared__ float red[1280];
    int tile = blockIdx.x, nh = blockIdx.y;
    int w = threadIdx.x >> 6, l = threadIdx.x & 63;
    int row = tile * 16 + (l & 15);
    int q = l >> 4;
    int cbeg = w * 16, cend = (cbeg + 16 < NCH) ? cbeg + 16 : NCH;
    f32x4 acc = {0.f, 0.f, 0.f, 0.f};
    const unsigned short* arow = WAbf + (size_t)row * KP + q * 8;
    const uint4* bbase = (const uint4*)fx_frag;
    for (int c = cbeg; c < cend; ++c) {
        uint4 a = *(const uint4*)(arow + c * 32);
        uint4 b = bbase[(c * 2 + nh) * 64 + l];
        acc = __builtin_amdgcn_mfma_f32_16x16x32_bf16(*(s16x8*)&a, *(s16x8*)&b, acc, 0, 0, 0);
    }
    float* my = &red[w * 320 + l * 5];
    #pragma unroll
    for (int r = 0; r < 4; ++r) my[r] = acc[r];
    __syncthreads();
    if (w == 0) {
        #pragma unroll
        for (int r = 0; r < 4; ++r) {
            float s = red[l * 5 + r] + red[320 + l * 5 + r]
                    + red[640 + l * 5 + r] + red[960 + l * 5 + r];
            int i = tile * 16 + (l >> 4) * 4 + r;
            int b = nh * 16 + (l & 15);
            int idx = (i << 5) + b;
            float e = v_cur[idx] - s;
            err_plain[idx] = e;
            if (i < N_V) err_frag[fragpos(i, b)] = f32_to_bf16(e);
        }
    }
}

// GEMM2: back = WB . err ; grid (76 tiles, 2 halves); fused v update + tanh.
__global__ __launch_bounds__(256) void k_gemm2(
        const unsigned short* __restrict__ WB, const unsigned short* __restrict__ err_frag,
        const float* __restrict__ err_plain, unsigned short* __restrict__ fx_frag,
        float* __restrict__ v_cur) {
    __shared__ float red[1280];
    int tile = blockIdx.x, nh = blockIdx.y;
    int w = threadIdx.x >> 6, l = threadIdx.x & 63;
    int row = tile * 16 + (l & 15);
    int q = l >> 4;
    int cbeg = w * 16, cend = (cbeg + 16 < NCH) ? cbeg + 16 : NCH;
    f32x4 acc = {0.f, 0.f, 0.f, 0.f};
    const unsigned short* arow = WB + (size_t)row * KP + q * 8;
    const uint4* bbase = (const uint4*)err_frag;
    for (int c = cbeg; c < cend; ++c) {
        uint4 a = *(const uint4*)(arow + c * 32);
        uint4 b = bbase[(c * 2 + nh) * 64 + l];
        acc = __builtin_amdgcn_mfma_f32_16x16x32_bf16(*(s16x8*)&a, *(s16x8*)&b, acc, 0, 0, 0);
    }
    float* my = &red[w * 320 + l * 5];
    #pragma unroll
    for (int r = 0; r < 4; ++r) my[r] = acc[r];
    __syncthreads();
    if (w == 0) {
        #pragma unroll
        for (int r = 0; r < 4; ++r) {
            float back = red[l * 5 + r] + red[320 + l * 5 + r]
                       + red[640 + l * 5 + r] + red[960 + l * 5 + r];
            int rr = tile * 16 + (l >> 4) * 4 + r;
            int j = N_SENS + rr;
            int b = nh * 16 + (l & 15);
            int idx = (j << 5) + b;
            float vold = v_cur[idx];
            float fxv = tanhf(vold);
            float e0 = err_plain[idx];
            float vn = vold - LR_VAL * (e0 - (1.f - fxv * fxv) * back);
            v_cur[idx] = vn;
            fx_frag[fragpos(j, b)] = f32_to_bf16(tanhf(vn));
        }
    }
}

// internal [vertex][32] -> output [batch][vertex] fp32
__global__ void k_out(const float* __restrict__ v, float* __restrict__ out) {
    int t = blockIdx.x * blockDim.x + threadIdx.x;
    if (t < NVB) {
        int b = t / N_V;
        int i = t - b * N_V;
        out[t] = v[(i << 5) + b];
    }
}

// input cast only (fallback path)
__global__ void k_cast_in(const float* __restrict__ vin, float* __restrict__ v) {
    int t = blockIdx.x * blockDim.x + threadIdx.x;
    if (t < NVB) {
        int i = t >> 5, b = t & 31;
        v[t] = vin[b * N_V + i];
    }
}

// ------------------------- fallback path (R4 CSR, proven) ----------------

__global__ void k_zero_i32(int* a, int n) {
    int t = blockIdx.x * blockDim.x + threadIdx.x;
    if (t < n) a[t] = 0;
}

__global__ void k_hist(const int* __restrict__ src, const int* __restrict__ dst,
                       int* cnt_dst, int* cnt_src) {
    int e = blockIdx.x * blockDim.x + threadIdx.x;
    if (e < N_E) {
        atomicAdd(&cnt_dst[dst[e]], 1);
        atomicAdd(&cnt_src[src[e]], 1);
    }
}

__global__ __launch_bounds__(1024) void k_scan(int* cnt_a, int* rp_a,
                                               int* cnt_b, int* rp_b) {
    __shared__ int sh[1024];
    int t = threadIdx.x;
    for (int pass = 0; pass < 2; ++pass) {
        int* cnt = pass ? cnt_b : cnt_a;
        int* rp  = pass ? rp_b  : rp_a;
        int i0 = 2 * t, i1 = 2 * t + 1;
        int c0 = (i0 < N_V) ? cnt[i0] : 0;
        int c1 = (i1 < N_V) ? cnt[i1] : 0;
        __syncthreads();
        sh[t] = c0 + c1;
        __syncthreads();
        for (int off = 1; off < 1024; off <<= 1) {
            int v = (t >= off) ? sh[t - off] : 0;
            __syncthreads();
            sh[t] += v;
            __syncthreads();
        }
        int incl = sh[t];
        int e0 = incl - (c0 + c1);
        int e1 = e0 + c0;
        if (i0 <= N_V) rp[i0] = e0;
        if (i1 <= N_V) rp[i1] = e1;
        if (i0 < N_V) cnt[i0] = e0;
        if (i1 < N_V) cnt[i1] = e1;
    }
}

__global__ void k_scatter(const int* __restrict__ src, const int* __restrict__ dst,
                          const float* __restrict__ w,
                          int* cur_dst, int* cur_src,
                          unsigned* __restrict__ pk_dst, unsigned* __restrict__ pk_src) {
    int e = blockIdx.x * blockDim.x + threadIdx.x;
    if (e < N_E) {
        int s = src[e], d = dst[e];
        unsigned wbits = (unsigned)f32_to_bf16(w[e]);
        int p = atomicAdd(&cur_dst[d], 1);
        pk_dst[p] = (wbits << 16) | (unsigned)s;
        int q = atomicAdd(&cur_src[s], 1);
        pk_src[q] = (wbits << 16) | (unsigned)d;
    }
}

__global__ void k_fx_csr(const float* __restrict__ v, unsigned short* __restrict__ fx) {
    int t = blockIdx.x * blockDim.x + threadIdx.x;
    if (t < NVB) {
        int i = t >> 5, b = t & 31;
        int h = b >> 4, b16 = b & 15;
        fx[h * NVH + i * 16 + b16] = f32_to_bf16(tanhf(v[t]));
    }
}

__global__ __launch_bounds__(256) void k_pred_err(
        const float* __restrict__ v, const unsigned short* __restrict__ fx,
        const int* __restrict__ rp, const unsigned* __restrict__ pk,
        unsigned short* __restrict__ err) {
    __shared__ unsigned short tab[NVH];
    int h  = blockIdx.x / 250;
    int vg = blockIdx.x % 250;
    {
        const uint4* g = (const uint4*)(fx + h * NVH);
        uint4* l = (uint4*)tab;
        for (int i = threadIdx.x; i < NVH / 8; i += 256) l[i] = g[i];
    }
    __syncthreads();
    int wave = threadIdx.x >> 6;
    int lane = threadIdx.x & 63;
    int b16 = lane & 15, epar = lane >> 4;
    for (int k = 0; k < 2; ++k) {
        int vid = vg * 8 + wave * 2 + k;
        int beg = rp[vid], end = rp[vid + 1];
        float sum = 0.f;
        for (int e = beg + epar; e < end; e += 4) {
            unsigned p = pk[e];
            float w = bits_to_f32(p & 0xFFFF0000u);
            int nb = (int)(p & 0xFFFFu);
            sum += w * bf16_to_f32(tab[nb * 16 + b16]);
        }
        sum += __shfl_xor(sum, 16, 64);
        sum += __shfl_xor(sum, 32, 64);
        if (epar == 0) {
            float vo = v[(vid << 5) + h * 16 + b16];
            err[h * NVH + vid * 16 + b16] = f32_to_bf16(vo - sum);
        }
    }
}

__global__ __launch_bounds__(256) void k_back_upd(
        const unsigned short* __restrict__ fx, const unsigned short* __restrict__ err,
        const int* __restrict__ rp, const unsigned* __restrict__ pk,
        float* __restrict__ v) {
    __shared__ unsigned short tab[NVH];
    int h  = blockIdx.x / 152;
    int vg = blockIdx.x % 152;
    {
        const uint4* g = (const uint4*)(err + h * NVH);
        uint4* l = (uint4*)tab;
        for (int i = threadIdx.x; i < NVH / 8; i += 256) l[i] = g[i];
    }
    __syncthreads();
    int wave = threadIdx.x >> 6;
    int lane = threadIdx.x & 63;
    int b16 = lane & 15, epar = lane >> 4;
    for (int k = 0; k < 2; ++k) {
        int vid = N_SENS + vg * 8 + wave * 2 + k;
        if (vid >= N_V) continue;
        int beg = rp[vid], end = rp[vid + 1];
        float sum = 0.f;
        for (int e = beg + epar; e < end; e += 4) {
            unsigned p = pk[e];
            float w = bits_to_f32(p & 0xFFFF0000u);
            int nb = (int)(p & 0xFFFFu);
            sum += w * bf16_to_f32(tab[nb * 16 + b16]);
        }
        sum += __shfl_xor(sum, 16, 64);
        sum += __shfl_xor(sum, 32, 64);
        if (epar == 0) {
            float e0  = bf16_to_f32(tab[vid * 16 + b16]);
            float fxv = bf16_to_f32(fx[h * NVH + vid * 16 + b16]);
            float dv = e0 - (1.f - fxv * fxv) * sum;
            v[(vid << 5) + h * 16 + b16] -= LR_VAL * dv;
        }
    }
}

// ------------------------- host -----------------------------------------

extern "C" void kernel_launch(void* const* d_in, const int* in_sizes, int n_in,
                              void* d_out, int out_size, void* d_ws, size_t ws_size,
                              hipStream_t stream) {
    const float* vals = (const float*)d_in[0];
    const float* wts  = (const float*)d_in[1];
    const int* ei = (const int*)d_in[2];
    const int* src = ei;
    const int* dst = ei + N_E;
    float* out = (float*)d_out;

    const int EB = (N_E + 255) / 256;

    // dense ws layout: WA | fx_frag | err_frag | v_cur | err_plain | WAbf | WB
    const size_t WA_N  = (size_t)MP * KP;          // 4,128,768 f32
    const size_t WAB_N = WA_N;                     // u16
    const size_t WB_N  = (size_t)MP2 * KP;         // 2,451,456 u16
    const size_t need  = WA_N * 4 + 2 * (size_t)FRAG_N * 2 + 65536 * 4 * 2
                       + WAB_N * 2 + WB_N * 2 + 256;

    if (ws_size >= need) {
        float* WA = (float*)d_ws;
        unsigned short* fx_frag  = (unsigned short*)(WA + WA_N);
        unsigned short* err_frag = fx_frag + FRAG_N;
        float* v_cur = (float*)(err_frag + FRAG_N);
        float* err_plain = v_cur + 65536;
        unsigned short* WAbf = (unsigned short*)(err_plain + 65536);
        unsigned short* WB = WAbf + WAB_N;

        const int zero4 = (int)((WA_N * 4 + 2 * (size_t)FRAG_N * 2) / 16);
        k_zero_u4<<<1024, 256, 0, stream>>>((uint4*)WA, zero4);
        k_accum<<<EB, 256, 0, stream>>>(src, dst, wts, WA);
        k_cvt<<<1024, 256, 0, stream>>>(WA, WAbf, (int)(WA_N / 8));
        k_tr<<<dim3(63, 38), 256, 0, stream>>>(WA, WB);
        k_init<<<250, 256, 0, stream>>>(vals, v_cur, fx_frag);

        for (int t = 0; t < T_STEPS; ++t) {
            k_gemm1<<<dim3(MP / 16, 2), 256, 0, stream>>>(WAbf, fx_frag, v_cur,
                                                          err_plain, err_frag);
            k_gemm2<<<dim3(MP2 / 16, 2), 256, 0, stream>>>(WB, err_frag, err_plain,
                                                           fx_frag, v_cur);
        }
        k_out<<<250, 256, 0, stream>>>(v_cur, out);
    } else {
        float* v_cur = (float*)d_ws;
        unsigned short* fx_g  = (unsigned short*)(v_cur + NVB);
        unsigned short* err_g = fx_g + NVB;
        int* rp_dst  = (int*)(err_g + NVB);
        int* rp_src  = rp_dst + 2048;
        int* cur_dst = rp_src + 2048;
        int* cur_src = cur_dst + 2048;
        unsigned* pk_dst = (unsigned*)(cur_src + 2048);
        unsigned* pk_src = pk_dst + N_E;

        k_zero_i32<<<16, 256, 0, stream>>>(cur_dst, 4096);
        k_hist<<<EB, 256, 0, stream>>>(src, dst, cur_dst, cur_src);
        k_scan<<<1, 1024, 0, stream>>>(cur_dst, rp_dst, cur_src, rp_src);
        k_scatter<<<EB, 256, 0, stream>>>(src, dst, wts, cur_dst, cur_src,
                                          pk_dst, pk_src);
        k_cast_in<<<250, 256, 0, stream>>>(vals, v_cur);
        for (int t = 0; t < T_STEPS; ++t) {
            k_fx_csr<<<250, 256, 0, stream>>>(v_cur, fx_g);
            k_pred_err<<<500, 256, 0, stream>>>(v_cur, fx_g, rp_dst, pk_dst, err_g);
            k_back_upd<<<304, 256, 0, stream>>>(fx_g, err_g, rp_src, pk_src, v_cur);
        }
        k_out<<<250, 256, 0, stream>>>(v_cur, out);
    }
}

// Round 8
// 185.628 us; speedup vs baseline: 3.0276x; 1.0449x over previous
//
#include <hip/hip_runtime.h>
#include <hip/hip_bf16.h>

// PCGraphConv: iterative predictive-coding message passing.
// N_V=2000, N_SENS=784, N_E=500000, BATCH=32, T=5, lr=0.1.
// R7: operand-swapped MFMA GEMMs with pre-swizzled weight fragments.
//  - WA fp32 master [2000][2016] via 500K uncontended atomicAdds (unchanged).
//  - WAbf: bf16 B-fragment order [125 tiles][63 chunks][64 lanes][8] -> every
//    weight load in GEMM1 is a contiguous wave-wide 1KB stream.
//  - WBf: same for the backward weights (WA transposed), 76 tiles.
//  - GEMM computes transposed tiles: D[m=batch][n=vertex]; A = fx/err frag
//    (m=batch, L2-hot 129KB), B = weights (streamed once per step).
//  - Each block fuses both batch-halves (2 accumulators, one B-load).
//  - err lives only as bf16 A-fragments; gemm2 epilogue fuses v-update+tanh.
// Fallback: proven R4 CSR path if ws too small.

#define N_V     2000
#define N_SENS  784
#define N_INT   (N_V - N_SENS)   // 1216
#define N_E     500000
#define T_STEPS 5
#define LR_VAL  0.1f
#define NVB     (N_V * 32)       // 64000
#define NVH     (N_V * 16)       // 32000
#define KP      2016             // padded K (63 chunks of 32)
#define NCH     63               // K chunks
#define NT1     125              // vertex tiles (all vertices, 125*16=2000)
#define NT2     76               // interior tiles (76*16=1216)
#define FRAG_N  (2 * NCH * 64 * 8)   // 64512 u16 per A-frag table (fx or err)

typedef float  f32x4 __attribute__((ext_vector_type(4)));
typedef short  s16x8 __attribute__((ext_vector_type(8)));

__device__ __forceinline__ float bits_to_f32(unsigned u) {
    union { unsigned u; float f; } c; c.u = u; return c.f;
}
__device__ __forceinline__ unsigned f32_to_bits(float f) {
    union { float f; unsigned u; } c; c.f = f; return c.u;
}
__device__ __forceinline__ unsigned short f32_to_bf16(float f) {
    unsigned u = f32_to_bits(f);
    return (unsigned short)((u + 0x7FFFu + ((u >> 16) & 1u)) >> 16);  // RNE
}
__device__ __forceinline__ float bf16_to_f32(unsigned short s) {
    return bits_to_f32((unsigned)s << 16);
}

// A-fragment u16 index for element (k, b) of fx/err tables (m = b&15).
__device__ __forceinline__ int aposKB(int k, int b) {
    int c = k >> 5, q = (k >> 3) & 3, j = k & 7;
    int h = b >> 4, m = b & 15;
    return (((h * NCH + c) * 64) + q * 16 + m) * 8 + j;
}

// ------------------------- dense/MFMA path -------------------------------

__global__ void k_zero_u4(uint4* p, int n4) {
    uint4 z = {0u, 0u, 0u, 0u};
    for (int t = blockIdx.x * blockDim.x + threadIdx.x; t < n4; t += gridDim.x * blockDim.x)
        p[t] = z;
}

__global__ void k_accum(const int* __restrict__ src, const int* __restrict__ dst,
                        const float* __restrict__ w, float* __restrict__ WA) {
    int e = blockIdx.x * blockDim.x + threadIdx.x;
    if (e < N_E) {
        atomicAdd(&WA[(size_t)dst[e] * KP + src[e]], w[e]);
    }
}

// WAbf[((tile*63+c)*64+l)*8+j] = bf16(WA[tile*16+(l&15)][c*32+(l>>4)*8+j])
__global__ void k_cvtA(const float* __restrict__ WA, uint4* __restrict__ WAbf4) {
    int t = blockIdx.x * blockDim.x + threadIdx.x;
    if (t < NT1 * NCH * 64) {
        int tile = t / (NCH * 64);
        int rem = t - tile * (NCH * 64);
        int c = rem >> 6, l = rem & 63;
        int row = tile * 16 + (l & 15);
        int col = c * 32 + (l >> 4) * 8;
        const float4* p = (const float4*)(WA + (size_t)row * KP + col);
        float4 a0 = p[0], a1 = p[1];
        unsigned short r[8];
        r[0] = f32_to_bf16(a0.x); r[1] = f32_to_bf16(a0.y);
        r[2] = f32_to_bf16(a0.z); r[3] = f32_to_bf16(a0.w);
        r[4] = f32_to_bf16(a1.x); r[5] = f32_to_bf16(a1.y);
        r[6] = f32_to_bf16(a1.z); r[7] = f32_to_bf16(a1.w);
        WAbf4[t] = *(const uint4*)r;
    }
}

// WBf[((tile*63+c)*64+l)*8+j] = bf16(WA[c*32+(l>>4)*8+j][784+tile*16+(l&15)])
__global__ void k_trB(const float* __restrict__ WA, uint4* __restrict__ WBf4) {
    int t = blockIdx.x * blockDim.x + threadIdx.x;
    if (t < NT2 * NCH * 64) {
        int tile = t / (NCH * 64);
        int rem = t - tile * (NCH * 64);
        int c = rem >> 6, l = rem & 63;
        int jcol = N_SENS + tile * 16 + (l & 15);
        int k0 = c * 32 + (l >> 4) * 8;
        unsigned short r[8];
        #pragma unroll
        for (int j = 0; j < 8; ++j) {
            float v = (k0 + j < N_V) ? WA[(size_t)(k0 + j) * KP + jcol] : 0.f;
            r[j] = f32_to_bf16(v);
        }
        WBf4[t] = *(const uint4*)r;
    }
}

// input [batch][vertex] fp32 -> v_cur [vertex][32] fp32 + fxA (bf16 tanh)
__global__ void k_init(const float* __restrict__ vin, float* __restrict__ v,
                       unsigned short* __restrict__ fxA) {
    int t = blockIdx.x * blockDim.x + threadIdx.x;
    if (t < NVB) {
        int i = t >> 5, b = t & 31;
        float x = vin[b * N_V + i];
        v[t] = x;
        fxA[aposKB(i, b)] = f32_to_bf16(tanhf(x));
    }
}

// GEMM1: err^T = v^T - fx^T . WA^T ; 125 blocks, 4 waves K-split, both halves.
__global__ __launch_bounds__(256) void k_gemm1(
        const uint4* __restrict__ WAbf4, const uint4* __restrict__ fxA4,
        const float* __restrict__ v_cur, unsigned short* __restrict__ errA) {
    __shared__ float red[2304];
    int tile = blockIdx.x;
    int w = threadIdx.x >> 6, l = threadIdx.x & 63;
    int cbeg = w * 16, cend = (cbeg + 16 < NCH) ? cbeg + 16 : NCH;
    f32x4 acc0 = {0.f, 0.f, 0.f, 0.f}, acc1 = {0.f, 0.f, 0.f, 0.f};
    for (int c = cbeg; c < cend; ++c) {
        uint4 bfrag = WAbf4[(tile * NCH + c) * 64 + l];
        uint4 a0 = fxA4[c * 64 + l];
        uint4 a1 = fxA4[(NCH + c) * 64 + l];
        acc0 = __builtin_amdgcn_mfma_f32_16x16x32_bf16(*(s16x8*)&a0, *(s16x8*)&bfrag, acc0, 0, 0, 0);
        acc1 = __builtin_amdgcn_mfma_f32_16x16x32_bf16(*(s16x8*)&a1, *(s16x8*)&bfrag, acc1, 0, 0, 0);
    }
    float* my = &red[w * 576 + l * 9];
    #pragma unroll
    for (int r = 0; r < 4; ++r) { my[r] = acc0[r]; my[4 + r] = acc1[r]; }
    __syncthreads();
    if (w == 0) {
        float s[8];
        #pragma unroll
        for (int r = 0; r < 8; ++r)
            s[r] = red[l * 9 + r] + red[576 + l * 9 + r]
                 + red[1152 + l * 9 + r] + red[1728 + l * 9 + r];
        int i = tile * 16 + (l & 15);
        int q = l >> 4;
        int c2 = i >> 5, q2 = (i >> 3) & 3, j2 = i & 7;
        #pragma unroll
        for (int h = 0; h < 2; ++h) {
            const float4 v4 = *(const float4*)(v_cur + (i << 5) + h * 16 + q * 4);
            int base = ((h * NCH + c2) * 64 + q2 * 16) * 8 + j2;
            errA[base + (q * 4 + 0) * 8] = f32_to_bf16(v4.x - s[h * 4 + 0]);
            errA[base + (q * 4 + 1) * 8] = f32_to_bf16(v4.y - s[h * 4 + 1]);
            errA[base + (q * 4 + 2) * 8] = f32_to_bf16(v4.z - s[h * 4 + 2]);
            errA[base + (q * 4 + 3) * 8] = f32_to_bf16(v4.w - s[h * 4 + 3]);
        }
    }
}

// GEMM2: back^T = err^T . WA ; 76 blocks; fused v update + tanh + fx repack.
__global__ __launch_bounds__(256) void k_gemm2(
        const uint4* __restrict__ WBf4, const uint4* __restrict__ errA4,
        unsigned short* __restrict__ errA, unsigned short* __restrict__ fxA,
        float* __restrict__ v_cur) {
    __shared__ float red[2304];
    int tile = blockIdx.x;
    int w = threadIdx.x >> 6, l = threadIdx.x & 63;
    int cbeg = w * 16, cend = (cbeg + 16 < NCH) ? cbeg + 16 : NCH;
    f32x4 acc0 = {0.f, 0.f, 0.f, 0.f}, acc1 = {0.f, 0.f, 0.f, 0.f};
    for (int c = cbeg; c < cend; ++c) {
        uint4 bfrag = WBf4[(tile * NCH + c) * 64 + l];
        uint4 a0 = errA4[c * 64 + l];
        uint4 a1 = errA4[(NCH + c) * 64 + l];
        acc0 = __builtin_amdgcn_mfma_f32_16x16x32_bf16(*(s16x8*)&a0, *(s16x8*)&bfrag, acc0, 0, 0, 0);
        acc1 = __builtin_amdgcn_mfma_f32_16x16x32_bf16(*(s16x8*)&a1, *(s16x8*)&bfrag, acc1, 0, 0, 0);
    }
    float* my = &red[w * 576 + l * 9];
    #pragma unroll
    for (int r = 0; r < 4; ++r) { my[r] = acc0[r]; my[4 + r] = acc1[r]; }
    __syncthreads();
    if (w == 0) {
        float s[8];
        #pragma unroll
        for (int r = 0; r < 8; ++r)
            s[r] = red[l * 9 + r] + red[576 + l * 9 + r]
                 + red[1152 + l * 9 + r] + red[1728 + l * 9 + r];
        int j = N_SENS + tile * 16 + (l & 15);
        int q = l >> 4;
        int c2 = j >> 5, q2 = (j >> 3) & 3, j2 = j & 7;
        #pragma unroll
        for (int h = 0; h < 2; ++h) {
            float4 v4 = *(const float4*)(v_cur + (j << 5) + h * 16 + q * 4);
            int base = ((h * NCH + c2) * 64 + q2 * 16) * 8 + j2;
            float vv[4] = {v4.x, v4.y, v4.z, v4.w};
            #pragma unroll
            for (int r = 0; r < 4; ++r) {
                float back = s[h * 4 + r];
                float e0 = bf16_to_f32(errA[base + (q * 4 + r) * 8]);
                float fxv = tanhf(vv[r]);
                float vn = vv[r] - LR_VAL * (e0 - (1.f - fxv * fxv) * back);
                vv[r] = vn;
                fxA[base + (q * 4 + r) * 8] = f32_to_bf16(tanhf(vn));
            }
            float4 o = {vv[0], vv[1], vv[2], vv[3]};
            *(float4*)(v_cur + (j << 5) + h * 16 + q * 4) = o;
        }
    }
}

// internal [vertex][32] -> output [batch][vertex] fp32
__global__ void k_out(const float* __restrict__ v, float* __restrict__ out) {
    int t = blockIdx.x * blockDim.x + threadIdx.x;
    if (t < NVB) {
        int b = t / N_V;
        int i = t - b * N_V;
        out[t] = v[(i << 5) + b];
    }
}

// input cast only (fallback path)
__global__ void k_cast_in(const float* __restrict__ vin, float* __restrict__ v) {
    int t = blockIdx.x * blockDim.x + threadIdx.x;
    if (t < NVB) {
        int i = t >> 5, b = t & 31;
        v[t] = vin[b * N_V + i];
    }
}

// ------------------------- fallback path (R4 CSR, proven) ----------------

__global__ void k_zero_i32(int* a, int n) {
    int t = blockIdx.x * blockDim.x + threadIdx.x;
    if (t < n) a[t] = 0;
}

__global__ void k_hist(const int* __restrict__ src, const int* __restrict__ dst,
                       int* cnt_dst, int* cnt_src) {
    int e = blockIdx.x * blockDim.x + threadIdx.x;
    if (e < N_E) {
        atomicAdd(&cnt_dst[dst[e]], 1);
        atomicAdd(&cnt_src[src[e]], 1);
    }
}

__global__ __launch_bounds__(1024) void k_scan(int* cnt_a, int* rp_a,
                                               int* cnt_b, int* rp_b) {
    __shared__ int sh[1024];
    int t = threadIdx.x;
    for (int pass = 0; pass < 2; ++pass) {
        int* cnt = pass ? cnt_b : cnt_a;
        int* rp  = pass ? rp_b  : rp_a;
        int i0 = 2 * t, i1 = 2 * t + 1;
        int c0 = (i0 < N_V) ? cnt[i0] : 0;
        int c1 = (i1 < N_V) ? cnt[i1] : 0;
        __syncthreads();
        sh[t] = c0 + c1;
        __syncthreads();
        for (int off = 1; off < 1024; off <<= 1) {
            int v = (t >= off) ? sh[t - off] : 0;
            __syncthreads();
            sh[t] += v;
            __syncthreads();
        }
        int incl = sh[t];
        int e0 = incl - (c0 + c1);
        int e1 = e0 + c0;
        if (i0 <= N_V) rp[i0] = e0;
        if (i1 <= N_V) rp[i1] = e1;
        if (i0 < N_V) cnt[i0] = e0;
        if (i1 < N_V) cnt[i1] = e1;
    }
}

__global__ void k_scatter(const int* __restrict__ src, const int* __restrict__ dst,
                          const float* __restrict__ w,
                          int* cur_dst, int* cur_src,
                          unsigned* __restrict__ pk_dst, unsigned* __restrict__ pk_src) {
    int e = blockIdx.x * blockDim.x + threadIdx.x;
    if (e < N_E) {
        int s = src[e], d = dst[e];
        unsigned wbits = (unsigned)f32_to_bf16(w[e]);
        int p = atomicAdd(&cur_dst[d], 1);
        pk_dst[p] = (wbits << 16) | (unsigned)s;
        int q = atomicAdd(&cur_src[s], 1);
        pk_src[q] = (wbits << 16) | (unsigned)d;
    }
}

__global__ void k_fx_csr(const float* __restrict__ v, unsigned short* __restrict__ fx) {
    int t = blockIdx.x * blockDim.x + threadIdx.x;
    if (t < NVB) {
        int i = t >> 5, b = t & 31;
        int h = b >> 4, b16 = b & 15;
        fx[h * NVH + i * 16 + b16] = f32_to_bf16(tanhf(v[t]));
    }
}

__global__ __launch_bounds__(256) void k_pred_err(
        const float* __restrict__ v, const unsigned short* __restrict__ fx,
        const int* __restrict__ rp, const unsigned* __restrict__ pk,
        unsigned short* __restrict__ err) {
    __shared__ unsigned short tab[NVH];
    int h  = blockIdx.x / 250;
    int vg = blockIdx.x % 250;
    {
        const uint4* g = (const uint4*)(fx + h * NVH);
        uint4* l = (uint4*)tab;
        for (int i = threadIdx.x; i < NVH / 8; i += 256) l[i] = g[i];
    }
    __syncthreads();
    int wave = threadIdx.x >> 6;
    int lane = threadIdx.x & 63;
    int b16 = lane & 15, epar = lane >> 4;
    for (int k = 0; k < 2; ++k) {
        int vid = vg * 8 + wave * 2 + k;
        int beg = rp[vid], end = rp[vid + 1];
        float sum = 0.f;
        for (int e = beg + epar; e < end; e += 4) {
            unsigned p = pk[e];
            float w = bits_to_f32(p & 0xFFFF0000u);
            int nb = (int)(p & 0xFFFFu);
            sum += w * bf16_to_f32(tab[nb * 16 + b16]);
        }
        sum += __shfl_xor(sum, 16, 64);
        sum += __shfl_xor(sum, 32, 64);
        if (epar == 0) {
            float vo = v[(vid << 5) + h * 16 + b16];
            err[h * NVH + vid * 16 + b16] = f32_to_bf16(vo - sum);
        }
    }
}

__global__ __launch_bounds__(256) void k_back_upd(
        const unsigned short* __restrict__ fx, const unsigned short* __restrict__ err,
        const int* __restrict__ rp, const unsigned* __restrict__ pk,
        float* __restrict__ v) {
    __shared__ unsigned short tab[NVH];
    int h  = blockIdx.x / 152;
    int vg = blockIdx.x % 152;
    {
        const uint4* g = (const uint4*)(err + h * NVH);
        uint4* l = (uint4*)tab;
        for (int i = threadIdx.x; i < NVH / 8; i += 256) l[i] = g[i];
    }
    __syncthreads();
    int wave = threadIdx.x >> 6;
    int lane = threadIdx.x & 63;
    int b16 = lane & 15, epar = lane >> 4;
    for (int k = 0; k < 2; ++k) {
        int vid = N_SENS + vg * 8 + wave * 2 + k;
        if (vid >= N_V) continue;
        int beg = rp[vid], end = rp[vid + 1];
        float sum = 0.f;
        for (int e = beg + epar; e < end; e += 4) {
            unsigned p = pk[e];
            float w = bits_to_f32(p & 0xFFFF0000u);
            int nb = (int)(p & 0xFFFFu);
            sum += w * bf16_to_f32(tab[nb * 16 + b16]);
        }
        sum += __shfl_xor(sum, 16, 64);
        sum += __shfl_xor(sum, 32, 64);
        if (epar == 0) {
            float e0  = bf16_to_f32(tab[vid * 16 + b16]);
            float fxv = bf16_to_f32(fx[h * NVH + vid * 16 + b16]);
            float dv = e0 - (1.f - fxv * fxv) * sum;
            v[(vid << 5) + h * 16 + b16] -= LR_VAL * dv;
        }
    }
}

// ------------------------- host -----------------------------------------

extern "C" void kernel_launch(void* const* d_in, const int* in_sizes, int n_in,
                              void* d_out, int out_size, void* d_ws, size_t ws_size,
                              hipStream_t stream) {
    const float* vals = (const float*)d_in[0];
    const float* wts  = (const float*)d_in[1];
    const int* ei = (const int*)d_in[2];
    const int* src = ei;
    const int* dst = ei + N_E;
    float* out = (float*)d_out;

    const int EB = (N_E + 255) / 256;

    // ws layout: WA | fxA | errA | v_cur | WAbf | WBf
    const size_t WA_N   = (size_t)N_V * KP;        // 4,032,000 f32
    const size_t WABF_T = (size_t)NT1 * NCH * 64;  // 504,000 uint4
    const size_t WBF_T  = (size_t)NT2 * NCH * 64;  // 306,432 uint4
    const size_t need = WA_N * 4 + 2 * (size_t)FRAG_N * 2 + NVB * 4
                      + WABF_T * 16 + WBF_T * 16 + 256;

    if (ws_size >= need) {
        float* WA = (float*)d_ws;
        unsigned short* fxA  = (unsigned short*)(WA + WA_N);
        unsigned short* errA = fxA + FRAG_N;
        float* v_cur = (float*)(errA + FRAG_N);
        uint4* WAbf4 = (uint4*)(v_cur + NVB);
        uint4* WBf4  = WAbf4 + WABF_T;

        // zero WA + both frag tables (contiguous)
        const int zero4 = (int)((WA_N * 4 + 2 * (size_t)FRAG_N * 2) / 16);
        k_zero_u4<<<1024, 256, 0, stream>>>((uint4*)WA, zero4);
        k_accum<<<EB, 256, 0, stream>>>(src, dst, wts, WA);
        k_cvtA<<<(int)((WABF_T + 255) / 256), 256, 0, stream>>>(WA, WAbf4);
        k_trB<<<(int)((WBF_T + 255) / 256), 256, 0, stream>>>(WA, WBf4);
        k_init<<<250, 256, 0, stream>>>(vals, v_cur, fxA);

        for (int t = 0; t < T_STEPS; ++t) {
            k_gemm1<<<NT1, 256, 0, stream>>>(WAbf4, (const uint4*)fxA, v_cur, errA);
            k_gemm2<<<NT2, 256, 0, stream>>>(WBf4, (const uint4*)errA, errA, fxA, v_cur);
        }
        k_out<<<250, 256, 0, stream>>>(v_cur, out);
    } else {
        float* v_cur = (float*)d_ws;
        unsigned short* fx_g  = (unsigned short*)(v_cur + NVB);
        unsigned short* err_g = fx_g + NVB;
        int* rp_dst  = (int*)(err_g + NVB);
        int* rp_src  = rp_dst + 2048;
        int* cur_dst = rp_src + 2048;
        int* cur_src = cur_dst + 2048;
        unsigned* pk_dst = (unsigned*)(cur_src + 2048);
        unsigned* pk_src = pk_dst + N_E;

        k_zero_i32<<<16, 256, 0, stream>>>(cur_dst, 4096);
        k_hist<<<EB, 256, 0, stream>>>(src, dst, cur_dst, cur_src);
        k_scan<<<1, 1024, 0, stream>>>(cur_dst, rp_dst, cur_src, rp_src);
        k_scatter<<<EB, 256, 0, stream>>>(src, dst, wts, cur_dst, cur_src,
                                          pk_dst, pk_src);
        k_cast_in<<<250, 256, 0, stream>>>(vals, v_cur);
        for (int t = 0; t < T_STEPS; ++t) {
            k_fx_csr<<<250, 256, 0, stream>>>(v_cur, fx_g);
            k_pred_err<<<500, 256, 0, stream>>>(v_cur, fx_g, rp_dst, pk_dst, err_g);
            k_back_upd<<<304, 256, 0, stream>>>(fx_g, err_g, rp_src, pk_src, v_cur);
        }
        k_out<<<250, 256, 0, stream>>>(v_cur, out);
    }
}

// Round 9
// 180.127 us; speedup vs baseline: 3.1201x; 1.0305x over previous
//
#include <hip/hip_runtime.h>
#include <hip/hip_bf16.h>

// PCGraphConv: iterative predictive-coding message passing.
// N_V=2000, N_SENS=784, N_E=500000, BATCH=32, T=5, lr=0.1.
// R8: counting-sort W-build (no random global atomics).
//  cnt -> scan_a -> scan_b -> place: edges sorted by dst-tile (125 tiles of 16
//  rows) into block-private contiguous ranges (write amp ~1x). build: per
//  tile-half, accumulate ~4000 sorted edges into LDS fp32 acc[8][2016], emit
//  WAbf MFMA B-fragments + dense bf16 WAd rows sequentially. trB transposes
//  WAd (bf16) into WBf fragments. GEMMs unchanged from R7 (operand-swapped
//  MFMA, weights streamed contiguously, fused epilogues).
// Fallback: proven R4 CSR path if ws too small.

#define N_V     2000
#define N_SENS  784
#define N_INT   (N_V - N_SENS)   // 1216
#define N_E     500000
#define T_STEPS 5
#define LR_VAL  0.1f
#define NVB     (N_V * 32)       // 64000
#define NVH     (N_V * 16)       // 32000
#define KP      2016             // padded K (63 chunks of 32)
#define NCH     63               // K chunks
#define NT1     125              // dst tiles (125*16 = 2000)
#define NT2     76               // interior src tiles (76*16 = 1216)
#define FRAG_N  (2 * NCH * 64 * 8)   // 64512 u16 per A-frag table
#define NBLK    250              // sort blocks
#define EPB     2000             // edges per sort block

typedef float  f32x4 __attribute__((ext_vector_type(4)));
typedef short  s16x8 __attribute__((ext_vector_type(8)));

__device__ __forceinline__ float bits_to_f32(unsigned u) {
    union { unsigned u; float f; } c; c.u = u; return c.f;
}
__device__ __forceinline__ unsigned f32_to_bits(float f) {
    union { float f; unsigned u; } c; c.f = f; return c.u;
}
__device__ __forceinline__ unsigned short f32_to_bf16(float f) {
    unsigned u = f32_to_bits(f);
    return (unsigned short)((u + 0x7FFFu + ((u >> 16) & 1u)) >> 16);  // RNE
}
__device__ __forceinline__ float bf16_to_f32(unsigned short s) {
    return bits_to_f32((unsigned)s << 16);
}

// A-fragment u16 index for element (k, b) of fx/err tables (m = b&15).
__device__ __forceinline__ int aposKB(int k, int b) {
    int c = k >> 5, q = (k >> 3) & 3, j = k & 7;
    int h = b >> 4, m = b & 15;
    return (((h * NCH + c) * 64) + q * 16 + m) * 8 + j;
}

// ------------------------- dense/MFMA path -------------------------------

__global__ void k_zero_u4(uint4* p, int n4) {
    uint4 z = {0u, 0u, 0u, 0u};
    for (int t = blockIdx.x * blockDim.x + threadIdx.x; t < n4; t += gridDim.x * blockDim.x)
        p[t] = z;
}

// histogram edges by dst-tile; cnt_g layout [tile][block]
__global__ __launch_bounds__(256) void k_cnt(const int* __restrict__ dst,
                                             int* __restrict__ cnt_g) {
    __shared__ int cnt[NT1];
    int b = blockIdx.x;
    for (int i = threadIdx.x; i < NT1; i += 256) cnt[i] = 0;
    __syncthreads();
    int base = b * EPB;
    for (int e = base + threadIdx.x; e < base + EPB; e += 256)
        atomicAdd(&cnt[dst[e] >> 4], 1);
    __syncthreads();
    for (int t = threadIdx.x; t < NT1; t += 256)
        cnt_g[t * 256 + b] = cnt[t];
}

// per-tile exclusive scan over blocks; totals[t] = tile edge count
__global__ __launch_bounds__(256) void k_scan_a(const int* __restrict__ cnt_g,
                                                int* __restrict__ base_g,
                                                int* __restrict__ totals) {
    __shared__ int sh[256];
    int t = blockIdx.x, tid = threadIdx.x;
    int v = (tid < NBLK) ? cnt_g[t * 256 + tid] : 0;
    sh[tid] = v;
    __syncthreads();
    for (int off = 1; off < 256; off <<= 1) {
        int x = (tid >= off) ? sh[tid - off] : 0;
        __syncthreads();
        sh[tid] += x;
        __syncthreads();
    }
    if (tid < NBLK) base_g[t * 256 + tid] = sh[tid] - v;   // exclusive
    if (tid == 255) totals[t] = sh[255];
}

// scan tile totals -> tile_start[0..125]
__global__ void k_scan_b(const int* __restrict__ totals, int* __restrict__ tile_start) {
    if (threadIdx.x == 0 && blockIdx.x == 0) {
        int acc = 0;
        for (int t = 0; t < NT1; ++t) { tile_start[t] = acc; acc += totals[t]; }
        tile_start[NT1] = acc;
    }
}

// place edges into sorted order: pk = (bf16w<<16)|(row4<<11)|src
__global__ __launch_bounds__(256) void k_place(
        const int* __restrict__ src, const int* __restrict__ dst,
        const float* __restrict__ w, const int* __restrict__ base_g,
        const int* __restrict__ tile_start, unsigned* __restrict__ pk_g) {
    __shared__ int cur[NT1];
    int b = blockIdx.x;
    for (int t = threadIdx.x; t < NT1; t += 256)
        cur[t] = tile_start[t] + base_g[t * 256 + b];
    __syncthreads();
    int base = b * EPB;
    for (int e = base + threadIdx.x; e < base + EPB; e += 256) {
        int d = dst[e];
        int tb = d >> 4;
        unsigned pk = ((unsigned)f32_to_bf16(w[e]) << 16)
                    | ((unsigned)(d & 15) << 11) | (unsigned)src[e];
        int p = atomicAdd(&cur[tb], 1);
        pk_g[p] = pk;
    }
}

// build WAbf fragments + dense bf16 WAd from sorted edges.
// 250 blocks: tile = bx>>1, half = bx&1 (rows half*8 .. half*8+7).
__global__ __launch_bounds__(256) void k_build(
        const unsigned* __restrict__ pk_g, const int* __restrict__ tile_start,
        uint4* __restrict__ WAbf4, unsigned short* __restrict__ WAd) {
    __shared__ float acc[8][KP];   // 64.5 KB
    int tile = blockIdx.x >> 1, half = blockIdx.x & 1;
    for (int i = threadIdx.x; i < 8 * KP / 4; i += 256)
        ((float4*)&acc[0][0])[i] = make_float4(0.f, 0.f, 0.f, 0.f);
    __syncthreads();
    int beg = tile_start[tile], end = tile_start[tile + 1];
    for (int e = beg + threadIdx.x; e < end; e += 256) {
        unsigned pk = pk_g[e];
        int row = (int)((pk >> 11) & 15u);
        if ((row >> 3) == half)
            atomicAdd(&acc[row & 7][pk & 0x7FFu], bf16_to_f32((unsigned short)(pk >> 16)));
    }
    __syncthreads();
    // emit: 8 rows x 252 col-groups of 8
    for (int i = threadIdx.x; i < 8 * 252; i += 256) {
        int rr = i / 252, g = i - rr * 252;
        int c = g >> 2, q = g & 3;
        int col = g * 8;
        unsigned short r[8];
        #pragma unroll
        for (int j = 0; j < 8; ++j) r[j] = f32_to_bf16(acc[rr][col + j]);
        uint4 val = *(const uint4*)r;
        int m = half * 8 + rr;
        WAbf4[((tile * NCH + c) * 64) + q * 16 + m] = val;
        *(uint4*)(WAd + (size_t)(tile * 16 + m) * KP + col) = val;
    }
}

// WBf[((tile*63+c)*64+l)*8+j] = WAd[c*32+(l>>4)*8+j][784+tile*16+(l&15)]
__global__ void k_trB(const unsigned short* __restrict__ WAd, uint4* __restrict__ WBf4) {
    int t = blockIdx.x * blockDim.x + threadIdx.x;
    if (t < NT2 * NCH * 64) {
        int tile = t / (NCH * 64);
        int rem = t - tile * (NCH * 64);
        int c = rem >> 6, l = rem & 63;
        int jcol = N_SENS + tile * 16 + (l & 15);
        int k0 = c * 32 + (l >> 4) * 8;
        unsigned short r[8];
        #pragma unroll
        for (int j = 0; j < 8; ++j)
            r[j] = (k0 + j < N_V) ? WAd[(size_t)(k0 + j) * KP + jcol] : (unsigned short)0;
        WBf4[t] = *(const uint4*)r;
    }
}

// input [batch][vertex] fp32 -> v_cur [vertex][32] fp32 + fxA (bf16 tanh)
__global__ void k_init(const float* __restrict__ vin, float* __restrict__ v,
                       unsigned short* __restrict__ fxA) {
    int t = blockIdx.x * blockDim.x + threadIdx.x;
    if (t < NVB) {
        int i = t >> 5, b = t & 31;
        float x = vin[b * N_V + i];
        v[t] = x;
        fxA[aposKB(i, b)] = f32_to_bf16(tanhf(x));
    }
}

// GEMM1: err^T = v^T - fx^T . WA^T ; 125 blocks, 4 waves K-split, both halves.
__global__ __launch_bounds__(256) void k_gemm1(
        const uint4* __restrict__ WAbf4, const uint4* __restrict__ fxA4,
        const float* __restrict__ v_cur, unsigned short* __restrict__ errA) {
    __shared__ float red[2304];
    int tile = blockIdx.x;
    int w = threadIdx.x >> 6, l = threadIdx.x & 63;
    int cbeg = w * 16, cend = (cbeg + 16 < NCH) ? cbeg + 16 : NCH;
    f32x4 acc0 = {0.f, 0.f, 0.f, 0.f}, acc1 = {0.f, 0.f, 0.f, 0.f};
    for (int c = cbeg; c < cend; ++c) {
        uint4 bfrag = WAbf4[(tile * NCH + c) * 64 + l];
        uint4 a0 = fxA4[c * 64 + l];
        uint4 a1 = fxA4[(NCH + c) * 64 + l];
        acc0 = __builtin_amdgcn_mfma_f32_16x16x32_bf16(*(s16x8*)&a0, *(s16x8*)&bfrag, acc0, 0, 0, 0);
        acc1 = __builtin_amdgcn_mfma_f32_16x16x32_bf16(*(s16x8*)&a1, *(s16x8*)&bfrag, acc1, 0, 0, 0);
    }
    float* my = &red[w * 576 + l * 9];
    #pragma unroll
    for (int r = 0; r < 4; ++r) { my[r] = acc0[r]; my[4 + r] = acc1[r]; }
    __syncthreads();
    if (w == 0) {
        float s[8];
        #pragma unroll
        for (int r = 0; r < 8; ++r)
            s[r] = red[l * 9 + r] + red[576 + l * 9 + r]
                 + red[1152 + l * 9 + r] + red[1728 + l * 9 + r];
        int i = tile * 16 + (l & 15);
        int q = l >> 4;
        int c2 = i >> 5, q2 = (i >> 3) & 3, j2 = i & 7;
        #pragma unroll
        for (int h = 0; h < 2; ++h) {
            const float4 v4 = *(const float4*)(v_cur + (i << 5) + h * 16 + q * 4);
            int base = ((h * NCH + c2) * 64 + q2 * 16) * 8 + j2;
            errA[base + (q * 4 + 0) * 8] = f32_to_bf16(v4.x - s[h * 4 + 0]);
            errA[base + (q * 4 + 1) * 8] = f32_to_bf16(v4.y - s[h * 4 + 1]);
            errA[base + (q * 4 + 2) * 8] = f32_to_bf16(v4.z - s[h * 4 + 2]);
            errA[base + (q * 4 + 3) * 8] = f32_to_bf16(v4.w - s[h * 4 + 3]);
        }
    }
}

// GEMM2: back^T = err^T . WA ; 76 blocks; fused v update + tanh + fx repack.
__global__ __launch_bounds__(256) void k_gemm2(
        const uint4* __restrict__ WBf4, const uint4* __restrict__ errA4,
        unsigned short* __restrict__ errA, unsigned short* __restrict__ fxA,
        float* __restrict__ v_cur) {
    __shared__ float red[2304];
    int tile = blockIdx.x;
    int w = threadIdx.x >> 6, l = threadIdx.x & 63;
    int cbeg = w * 16, cend = (cbeg + 16 < NCH) ? cbeg + 16 : NCH;
    f32x4 acc0 = {0.f, 0.f, 0.f, 0.f}, acc1 = {0.f, 0.f, 0.f, 0.f};
    for (int c = cbeg; c < cend; ++c) {
        uint4 bfrag = WBf4[(tile * NCH + c) * 64 + l];
        uint4 a0 = errA4[c * 64 + l];
        uint4 a1 = errA4[(NCH + c) * 64 + l];
        acc0 = __builtin_amdgcn_mfma_f32_16x16x32_bf16(*(s16x8*)&a0, *(s16x8*)&bfrag, acc0, 0, 0, 0);
        acc1 = __builtin_amdgcn_mfma_f32_16x16x32_bf16(*(s16x8*)&a1, *(s16x8*)&bfrag, acc1, 0, 0, 0);
    }
    float* my = &red[w * 576 + l * 9];
    #pragma unroll
    for (int r = 0; r < 4; ++r) { my[r] = acc0[r]; my[4 + r] = acc1[r]; }
    __syncthreads();
    if (w == 0) {
        float s[8];
        #pragma unroll
        for (int r = 0; r < 8; ++r)
            s[r] = red[l * 9 + r] + red[576 + l * 9 + r]
                 + red[1152 + l * 9 + r] + red[1728 + l * 9 + r];
        int j = N_SENS + tile * 16 + (l & 15);
        int q = l >> 4;
        int c2 = j >> 5, q2 = (j >> 3) & 3, j2 = j & 7;
        #pragma unroll
        for (int h = 0; h < 2; ++h) {
            float4 v4 = *(const float4*)(v_cur + (j << 5) + h * 16 + q * 4);
            int base = ((h * NCH + c2) * 64 + q2 * 16) * 8 + j2;
            float vv[4] = {v4.x, v4.y, v4.z, v4.w};
            #pragma unroll
            for (int r = 0; r < 4; ++r) {
                float back = s[h * 4 + r];
                float e0 = bf16_to_f32(errA[base + (q * 4 + r) * 8]);
                float fxv = tanhf(vv[r]);
                float vn = vv[r] - LR_VAL * (e0 - (1.f - fxv * fxv) * back);
                vv[r] = vn;
                fxA[base + (q * 4 + r) * 8] = f32_to_bf16(tanhf(vn));
            }
            float4 o = {vv[0], vv[1], vv[2], vv[3]};
            *(float4*)(v_cur + (j << 5) + h * 16 + q * 4) = o;
        }
    }
}

// internal [vertex][32] -> output [batch][vertex] fp32
__global__ void k_out(const float* __restrict__ v, float* __restrict__ out) {
    int t = blockIdx.x * blockDim.x + threadIdx.x;
    if (t < NVB) {
        int b = t / N_V;
        int i = t - b * N_V;
        out[t] = v[(i << 5) + b];
    }
}

// input cast only (fallback path)
__global__ void k_cast_in(const float* __restrict__ vin, float* __restrict__ v) {
    int t = blockIdx.x * blockDim.x + threadIdx.x;
    if (t < NVB) {
        int i = t >> 5, b = t & 31;
        v[t] = vin[b * N_V + i];
    }
}

// ------------------------- fallback path (R4 CSR, proven) ----------------

__global__ void k_zero_i32(int* a, int n) {
    int t = blockIdx.x * blockDim.x + threadIdx.x;
    if (t < n) a[t] = 0;
}

__global__ void k_hist(const int* __restrict__ src, const int* __restrict__ dst,
                       int* cnt_dst, int* cnt_src) {
    int e = blockIdx.x * blockDim.x + threadIdx.x;
    if (e < N_E) {
        atomicAdd(&cnt_dst[dst[e]], 1);
        atomicAdd(&cnt_src[src[e]], 1);
    }
}

__global__ __launch_bounds__(1024) void k_scan(int* cnt_a, int* rp_a,
                                               int* cnt_b, int* rp_b) {
    __shared__ int sh[1024];
    int t = threadIdx.x;
    for (int pass = 0; pass < 2; ++pass) {
        int* cnt = pass ? cnt_b : cnt_a;
        int* rp  = pass ? rp_b  : rp_a;
        int i0 = 2 * t, i1 = 2 * t + 1;
        int c0 = (i0 < N_V) ? cnt[i0] : 0;
        int c1 = (i1 < N_V) ? cnt[i1] : 0;
        __syncthreads();
        sh[t] = c0 + c1;
        __syncthreads();
        for (int off = 1; off < 1024; off <<= 1) {
            int v = (t >= off) ? sh[t - off] : 0;
            __syncthreads();
            sh[t] += v;
            __syncthreads();
        }
        int incl = sh[t];
        int e0 = incl - (c0 + c1);
        int e1 = e0 + c0;
        if (i0 <= N_V) rp[i0] = e0;
        if (i1 <= N_V) rp[i1] = e1;
        if (i0 < N_V) cnt[i0] = e0;
        if (i1 < N_V) cnt[i1] = e1;
    }
}

__global__ void k_scatter(const int* __restrict__ src, const int* __restrict__ dst,
                          const float* __restrict__ w,
                          int* cur_dst, int* cur_src,
                          unsigned* __restrict__ pk_dst, unsigned* __restrict__ pk_src) {
    int e = blockIdx.x * blockDim.x + threadIdx.x;
    if (e < N_E) {
        int s = src[e], d = dst[e];
        unsigned wbits = (unsigned)f32_to_bf16(w[e]);
        int p = atomicAdd(&cur_dst[d], 1);
        pk_dst[p] = (wbits << 16) | (unsigned)s;
        int q = atomicAdd(&cur_src[s], 1);
        pk_src[q] = (wbits << 16) | (unsigned)d;
    }
}

__global__ void k_fx_csr(const float* __restrict__ v, unsigned short* __restrict__ fx) {
    int t = blockIdx.x * blockDim.x + threadIdx.x;
    if (t < NVB) {
        int i = t >> 5, b = t & 31;
        int h = b >> 4, b16 = b & 15;
        fx[h * NVH + i * 16 + b16] = f32_to_bf16(tanhf(v[t]));
    }
}

__global__ __launch_bounds__(256) void k_pred_err(
        const float* __restrict__ v, const unsigned short* __restrict__ fx,
        const int* __restrict__ rp, const unsigned* __restrict__ pk,
        unsigned short* __restrict__ err) {
    __shared__ unsigned short tab[NVH];
    int h  = blockIdx.x / 250;
    int vg = blockIdx.x % 250;
    {
        const uint4* g = (const uint4*)(fx + h * NVH);
        uint4* l = (uint4*)tab;
        for (int i = threadIdx.x; i < NVH / 8; i += 256) l[i] = g[i];
    }
    __syncthreads();
    int wave = threadIdx.x >> 6;
    int lane = threadIdx.x & 63;
    int b16 = lane & 15, epar = lane >> 4;
    for (int k = 0; k < 2; ++k) {
        int vid = vg * 8 + wave * 2 + k;
        int beg = rp[vid], end = rp[vid + 1];
        float sum = 0.f;
        for (int e = beg + epar; e < end; e += 4) {
            unsigned p = pk[e];
            float w = bits_to_f32(p & 0xFFFF0000u);
            int nb = (int)(p & 0xFFFFu);
            sum += w * bf16_to_f32(tab[nb * 16 + b16]);
        }
        sum += __shfl_xor(sum, 16, 64);
        sum += __shfl_xor(sum, 32, 64);
        if (epar == 0) {
            float vo = v[(vid << 5) + h * 16 + b16];
            err[h * NVH + vid * 16 + b16] = f32_to_bf16(vo - sum);
        }
    }
}

__global__ __launch_bounds__(256) void k_back_upd(
        const unsigned short* __restrict__ fx, const unsigned short* __restrict__ err,
        const int* __restrict__ rp, const unsigned* __restrict__ pk,
        float* __restrict__ v) {
    __shared__ unsigned short tab[NVH];
    int h  = blockIdx.x / 152;
    int vg = blockIdx.x % 152;
    {
        const uint4* g = (const uint4*)(err + h * NVH);
        uint4* l = (uint4*)tab;
        for (int i = threadIdx.x; i < NVH / 8; i += 256) l[i] = g[i];
    }
    __syncthreads();
    int wave = threadIdx.x >> 6;
    int lane = threadIdx.x & 63;
    int b16 = lane & 15, epar = lane >> 4;
    for (int k = 0; k < 2; ++k) {
        int vid = N_SENS + vg * 8 + wave * 2 + k;
        if (vid >= N_V) continue;
        int beg = rp[vid], end = rp[vid + 1];
        float sum = 0.f;
        for (int e = beg + epar; e < end; e += 4) {
            unsigned p = pk[e];
            float w = bits_to_f32(p & 0xFFFF0000u);
            int nb = (int)(p & 0xFFFFu);
            sum += w * bf16_to_f32(tab[nb * 16 + b16]);
        }
        sum += __shfl_xor(sum, 16, 64);
        sum += __shfl_xor(sum, 32, 64);
        if (epar == 0) {
            float e0  = bf16_to_f32(tab[vid * 16 + b16]);
            float fxv = bf16_to_f32(fx[h * NVH + vid * 16 + b16]);
            float dv = e0 - (1.f - fxv * fxv) * sum;
            v[(vid << 5) + h * 16 + b16] -= LR_VAL * dv;
        }
    }
}

// ------------------------- host -----------------------------------------

extern "C" void kernel_launch(void* const* d_in, const int* in_sizes, int n_in,
                              void* d_out, int out_size, void* d_ws, size_t ws_size,
                              hipStream_t stream) {
    const float* vals = (const float*)d_in[0];
    const float* wts  = (const float*)d_in[1];
    const int* ei = (const int*)d_in[2];
    const int* src = ei;
    const int* dst = ei + N_E;
    float* out = (float*)d_out;

    const int EB = (N_E + 255) / 256;

    // ws layout: pk_g | cnt_g | base_g | totals | tile_start | WAd | WAbf | WBf
    //            | fxA | errA | v_cur
    const size_t WABF_T = (size_t)NT1 * NCH * 64;  // 504,000 uint4
    const size_t WBF_T  = (size_t)NT2 * NCH * 64;  // 306,432 uint4
    const size_t WAD_N  = (size_t)N_V * KP;        // 4,032,000 u16
    const size_t need = (size_t)N_E * 4 + 2 * NT1 * 256 * 4 + 512 * 4
                      + WAD_N * 2 + WABF_T * 16 + WBF_T * 16
                      + 2 * (size_t)FRAG_N * 2 + NVB * 4 + 256;

    if (ws_size >= need) {
        unsigned* pk_g = (unsigned*)d_ws;                     // 2 MB
        int* cnt_g  = (int*)(pk_g + N_E);                     // 128 KB
        int* base_g = cnt_g + NT1 * 256;                      // 128 KB
        int* totals = base_g + NT1 * 256;                     // 512 B
        int* tile_start = totals + 128;                       // 512 B
        unsigned short* WAd = (unsigned short*)(tile_start + 384);  // 8.06 MB
        uint4* WAbf4 = (uint4*)(WAd + WAD_N);                 // 8.06 MB
        uint4* WBf4  = WAbf4 + WABF_T;                        // 4.9 MB
        unsigned short* fxA  = (unsigned short*)(WBf4 + WBF_T);   // 129 KB
        unsigned short* errA = fxA + FRAG_N;                  // 129 KB
        float* v_cur = (float*)(errA + FRAG_N);               // 256 KB

        // zero frag tables (pad slots must be 0); everything else fully written
        k_zero_u4<<<64, 256, 0, stream>>>((uint4*)fxA, (int)(2 * (size_t)FRAG_N * 2 / 16));
        k_cnt<<<NBLK, 256, 0, stream>>>(dst, cnt_g);
        k_scan_a<<<NT1, 256, 0, stream>>>(cnt_g, base_g, totals);
        k_scan_b<<<1, 64, 0, stream>>>(totals, tile_start);
        k_place<<<NBLK, 256, 0, stream>>>(src, dst, wts, base_g, tile_start, pk_g);
        k_build<<<2 * NT1, 256, 0, stream>>>(pk_g, tile_start, WAbf4, WAd);
        k_trB<<<(int)((WBF_T + 255) / 256), 256, 0, stream>>>(WAd, WBf4);
        k_init<<<250, 256, 0, stream>>>(vals, v_cur, fxA);

        for (int t = 0; t < T_STEPS; ++t) {
            k_gemm1<<<NT1, 256, 0, stream>>>(WAbf4, (const uint4*)fxA, v_cur, errA);
            k_gemm2<<<NT2, 256, 0, stream>>>(WBf4, (const uint4*)errA, errA, fxA, v_cur);
        }
        k_out<<<250, 256, 0, stream>>>(v_cur, out);
    } else {
        float* v_cur = (float*)d_ws;
        unsigned short* fx_g  = (unsigned short*)(v_cur + NVB);
        unsigned short* err_g = fx_g + NVB;
        int* rp_dst  = (int*)(err_g + NVB);
        int* rp_src  = rp_dst + 2048;
        int* cur_dst = rp_src + 2048;
        int* cur_src = cur_dst + 2048;
        unsigned* pk_dst = (unsigned*)(cur_src + 2048);
        unsigned* pk_src = pk_dst + N_E;

        k_zero_i32<<<16, 256, 0, stream>>>(cur_dst, 4096);
        k_hist<<<EB, 256, 0, stream>>>(src, dst, cur_dst, cur_src);
        k_scan<<<1, 1024, 0, stream>>>(cur_dst, rp_dst, cur_src, rp_src);
        k_scatter<<<EB, 256, 0, stream>>>(src, dst, wts, cur_dst, cur_src,
                                          pk_dst, pk_src);
        k_cast_in<<<250, 256, 0, stream>>>(vals, v_cur);
        for (int t = 0; t < T_STEPS; ++t) {
            k_fx_csr<<<250, 256, 0, stream>>>(v_cur, fx_g);
            k_pred_err<<<500, 256, 0, stream>>>(v_cur, fx_g, rp_dst, pk_dst, err_g);
            k_back_upd<<<304, 256, 0, stream>>>(fx_g, err_g, rp_src, pk_src, v_cur);
        }
        k_out<<<250, 256, 0, stream>>>(v_cur, out);
    }
}